// Round 1
// baseline (388.270 us; speedup 1.0000x reference)
//
#include <hip/hip_runtime.h>
#include <hip/hip_bf16.h>

typedef __attribute__((ext_vector_type(8))) short s8v;
typedef __attribute__((ext_vector_type(4))) float f4v;

typedef __attribute__((address_space(1))) const void as1_void;
typedef __attribute__((address_space(3))) void as3_void;

__device__ __forceinline__ void gl16(const void* g, void* l) {
  __builtin_amdgcn_global_load_lds((as1_void*)g, (as3_void*)l, 16, 0, 0);
}

__device__ __forceinline__ float b2f(int u) {
  union { float f; unsigned i; } c; c.i = ((unsigned)(u & 0xFFFF)) << 16; return c.f;
}
__device__ __forceinline__ unsigned short f2b(float f) {
  union { float f; unsigned i; } c; c.f = f;
  unsigned r = c.i + 0x7FFFu + ((c.i >> 16) & 1u);
  return (unsigned short)(r >> 16);
}

#define MFMA16(a, b, c) __builtin_amdgcn_mfma_f32_16x16x32_bf16((a), (b), (c), 0, 0, 0)

// ---------------- weight convert + transpose: Wt[n][k] = bf16(W[k][n]) ----------------
__global__ __launch_bounds__(256) void conv_t(const float* __restrict__ W,
    unsigned short* __restrict__ Wt, int K, int N) {
  __shared__ float tile[32][33];
  const int tx = threadIdx.x & 31, ty = threadIdx.x >> 5;  // ty 0..7
  const int bn = blockIdx.x, bk = blockIdx.y;
#pragma unroll
  for (int i = 0; i < 32; i += 8)
    tile[ty + i][tx] = W[(size_t)(bk * 32 + ty + i) * N + bn * 32 + tx];
  __syncthreads();
#pragma unroll
  for (int i = 0; i < 32; i += 8)
    Wt[(size_t)(bn * 32 + ty + i) * K + bk * 32 + tx] = f2b(tile[tx][ty + i]);
}

// ---------------- RMSNorm: fp32 in -> bf16 out, D=768 ----------------
__global__ __launch_bounds__(256) void rmsnorm_k(const float* __restrict__ x,
    const float* __restrict__ w, unsigned short* __restrict__ out) {
  const int row = blockIdx.x, tid = threadIdx.x;
  const float* xr = x + (size_t)row * 768;
  float v0 = xr[tid], v1 = xr[tid + 256], v2 = xr[tid + 512];
  float ss = v0 * v0 + v1 * v1 + v2 * v2;
#pragma unroll
  for (int m = 1; m < 64; m <<= 1) ss += __shfl_xor(ss, m, 64);
  __shared__ float sred[4];
  if ((tid & 63) == 0) sred[tid >> 6] = ss;
  __syncthreads();
  const float tot = sred[0] + sred[1] + sred[2] + sred[3];
  const float rn = rsqrtf(tot * (1.0f / 768.0f) + 1e-6f);
  unsigned short* orow = out + (size_t)row * 768;
  orow[tid]       = f2b(v0 * rn * w[tid]);
  orow[tid + 256] = f2b(v1 * rn * w[tid + 256]);
  orow[tid + 512] = f2b(v2 * rn * w[tid + 512]);
}

// ---------------- RoPE cos/sin table: [4096][32] ----------------
__global__ __launch_bounds__(256) void rope_table_k(float* __restrict__ ct, float* __restrict__ st) {
  const int t = blockIdx.x * 256 + threadIdx.x;  // 4096*32
  const int s = t >> 5, d = t & 31;
  const float inv = powf(10000.0f, -(float)d * (1.0f / 32.0f));
  const float ang = (float)s * inv;
  ct[t] = cosf(ang);
  st[t] = sinf(ang);
}

// ---------------- RoPE in-place on qkv[4096][2304] (q and k regions) ----------------
__global__ __launch_bounds__(256) void rope_k(unsigned short* __restrict__ qkv,
    const float* __restrict__ ct, const float* __restrict__ st) {
  const int t = blockIdx.x * 256 + threadIdx.x;  // 4096*768 pairs
  const int s = t / 768, j = t - s * 768;
  const int which = j / 384;            // 0 = q, 1 = k
  const int jj = j - which * 384;
  const int hh = jj >> 5, d = jj & 31;
  const size_t base = (size_t)s * 2304 + which * 768 + hh * 64 + d;
  const float c = ct[s * 32 + d], sn = st[s * 32 + d];
  const float a = b2f(qkv[base]), b = b2f(qkv[base + 32]);
  qkv[base]      = f2b(a * c - b * sn);
  qkv[base + 32] = f2b(b * c + a * sn);
}

// ---------------- GEMM: C[M,N] = A[M,K](bf16) * Bt[N,K](bf16)^T ----------------
// EPI 0: bf16 store; EPI 1: fp32 store + fp32 residual add
template <int EPI>
__global__ __launch_bounds__(256) void gemm_bt(const unsigned short* __restrict__ A,
    const unsigned short* __restrict__ Bt, unsigned short* __restrict__ Cb,
    float* __restrict__ Cf, const float* __restrict__ R, int K, int ldc) {
  __shared__ unsigned short As[128 * 32];
  __shared__ unsigned short Bs[128 * 32];
  const int tid = threadIdx.x;
  const int lane = tid & 63, wid = tid >> 6;
  const int wr = wid >> 1, wc = wid & 1;
  const int l15 = lane & 15, l4 = lane >> 4;
  const int bm = blockIdx.y, bn = blockIdx.x;

  f4v acc[4][4] = {};

  const int o0 = tid * 16, o1 = tid * 16 + 4096;       // tile byte offsets
  const int r0 = o0 >> 6, c0 = o0 & 63;
  const int r1 = o1 >> 6, c1 = o1 & 63;
  const size_t ldab = (size_t)K * 2;
  const char* Abyte = (const char*)A;
  const char* Bbyte = (const char*)Bt;
  const size_t a0 = (size_t)(bm * 128 + r0) * ldab + c0;
  const size_t a1 = (size_t)(bm * 128 + r1) * ldab + c1;
  const size_t b0 = (size_t)(bn * 128 + r0) * ldab + c0;
  const size_t b1 = (size_t)(bn * 128 + r1) * ldab + c1;
  char* AsB = (char*)As;
  char* BsB = (char*)Bs;
  const int uoff = (tid >> 6) << 10;  // wave-uniform LDS byte base

  for (int k0 = 0; k0 < K; k0 += 32) {
    __syncthreads();
    const size_t kb = (size_t)k0 * 2;
    gl16(Abyte + a0 + kb, AsB + uoff);
    gl16(Abyte + a1 + kb, AsB + uoff + 4096);
    gl16(Bbyte + b0 + kb, BsB + uoff);
    gl16(Bbyte + b1 + kb, BsB + uoff + 4096);
    __syncthreads();
    s8v af[4], bf[4];
#pragma unroll
    for (int m = 0; m < 4; ++m)
      af[m] = *(const s8v*)(AsB + (wr * 64 + m * 16 + l15) * 64 + l4 * 16);
#pragma unroll
    for (int n = 0; n < 4; ++n)
      bf[n] = *(const s8v*)(BsB + (wc * 64 + n * 16 + l15) * 64 + l4 * 16);
#pragma unroll
    for (int m = 0; m < 4; ++m)
#pragma unroll
      for (int n = 0; n < 4; ++n) acc[m][n] = MFMA16(af[m], bf[n], acc[m][n]);
  }

  const int row0 = bm * 128 + wr * 64, col0 = bn * 128 + wc * 64;
#pragma unroll
  for (int m = 0; m < 4; ++m)
#pragma unroll
    for (int n = 0; n < 4; ++n)
#pragma unroll
      for (int r = 0; r < 4; ++r) {
        const int row = row0 + m * 16 + l4 * 4 + r;
        const int col = col0 + n * 16 + l15;
        const float v = acc[m][n][r];
        if (EPI == 0) {
          Cb[(size_t)row * ldc + col] = f2b(v);
        } else {
          Cf[(size_t)row * ldc + col] = v + R[(size_t)row * ldc + col];
        }
      }
}

// ---------------- causal flash attention ----------------
// qkv [4096][2304] bf16 (q|k|v, rope applied); out [4096][768] bf16
__global__ __launch_bounds__(256) void flash_k(const unsigned short* __restrict__ qkv,
    unsigned short* __restrict__ out) {
  const int h = blockIdx.y;
  const int qb = 63 - (int)blockIdx.x;  // long blocks first
  const int tid = threadIdx.x;
  const int wv = tid >> 6, lane = tid & 63;
  const int l15 = lane & 15, l4 = lane >> 4;

  __shared__ unsigned short Ks[64 * 72];      // [key][d] padded
  __shared__ unsigned short Vt[64 * 72];      // [d][key] padded (transposed)
  __shared__ unsigned short Pb[4][16 * 72];   // per-wave P staging

  const unsigned short* qp = qkv + h * 64;
  const unsigned short* kp = qkv + 768 + h * 64;
  const unsigned short* vp = qkv + 1536 + h * 64;

  const int qrow = qb * 64 + wv * 16 + l15;
  const s8v qf0 = *(const s8v*)(qp + (size_t)qrow * 2304 + l4 * 8);
  const s8v qf1 = *(const s8v*)(qp + (size_t)qrow * 2304 + 32 + l4 * 8);

  f4v o_acc[4] = {};
  float m_r[4], l_r[4];
#pragma unroll
  for (int r = 0; r < 4; ++r) { m_r[r] = -1e30f; l_r[r] = 0.f; }

  const int krow = tid >> 3, kc = (tid & 7) * 8;  // K staging: rows 0..31 (+32)
  const int vkey = tid & 63, vd0 = (tid >> 6) * 16;

  for (int t = 0; t <= qb; ++t) {
    const int k0 = t * 64;
    __syncthreads();
    // stage K [64][72]
    {
      s8v ka = *(const s8v*)(kp + (size_t)(k0 + krow) * 2304 + kc);
      s8v kb = *(const s8v*)(kp + (size_t)(k0 + krow + 32) * 2304 + kc);
      *(s8v*)(Ks + krow * 72 + kc) = ka;
      *(s8v*)(Ks + (krow + 32) * 72 + kc) = kb;
    }
    // stage V transposed -> Vt[d][key]
    {
      s8v va = *(const s8v*)(vp + (size_t)(k0 + vkey) * 2304 + vd0);
      s8v vb = *(const s8v*)(vp + (size_t)(k0 + vkey) * 2304 + vd0 + 8);
#pragma unroll
      for (int i = 0; i < 8; ++i) {
        Vt[(vd0 + i) * 72 + vkey]     = (unsigned short)va[i];
        Vt[(vd0 + 8 + i) * 72 + vkey] = (unsigned short)vb[i];
      }
    }
    __syncthreads();

    // scores S[16 q][64 key]
    f4v s_acc[4] = {};
#pragma unroll
    for (int n = 0; n < 4; ++n) {
      s8v kf0 = *(const s8v*)(Ks + (n * 16 + l15) * 72 + l4 * 8);
      s8v kf1 = *(const s8v*)(Ks + (n * 16 + l15) * 72 + 32 + l4 * 8);
      s_acc[n] = MFMA16(qf0, kf0, s_acc[n]);
      s_acc[n] = MFMA16(qf1, kf1, s_acc[n]);
    }

    float sv[4][4];
    float rmax[4] = {-1e30f, -1e30f, -1e30f, -1e30f};
    const bool diag = (t == qb);
#pragma unroll
    for (int n = 0; n < 4; ++n)
#pragma unroll
      for (int r = 0; r < 4; ++r) {
        float xv = s_acc[n][r] * 0.125f;
        if (diag && (k0 + n * 16 + l15 > qb * 64 + wv * 16 + l4 * 4 + r)) xv = -1e30f;
        sv[n][r] = xv;
        rmax[r] = fmaxf(rmax[r], xv);
      }
#pragma unroll
    for (int mm = 1; mm < 16; mm <<= 1)
#pragma unroll
      for (int r = 0; r < 4; ++r) rmax[r] = fmaxf(rmax[r], __shfl_xor(rmax[r], mm, 64));

    float corr[4], psum[4];
#pragma unroll
    for (int r = 0; r < 4; ++r) {
      const float mn = fmaxf(m_r[r], rmax[r]);
      corr[r] = __expf(m_r[r] - mn);
      m_r[r] = mn;
      psum[r] = 0.f;
    }
#pragma unroll
    for (int n = 0; n < 4; ++n)
#pragma unroll
      for (int r = 0; r < 4; ++r) {
        const float p = __expf(sv[n][r] - m_r[r]);
        sv[n][r] = p;
        psum[r] += p;
      }
#pragma unroll
    for (int mm = 1; mm < 16; mm <<= 1)
#pragma unroll
      for (int r = 0; r < 4; ++r) psum[r] += __shfl_xor(psum[r], mm, 64);
#pragma unroll
    for (int r = 0; r < 4; ++r) l_r[r] = l_r[r] * corr[r] + psum[r];
#pragma unroll
    for (int n = 0; n < 4; ++n)
#pragma unroll
      for (int r = 0; r < 4; ++r) o_acc[n][r] *= corr[r];

    // write P (bf16) to per-wave LDS, re-read as A-fragments
    unsigned short* pb = &Pb[wv][0];
#pragma unroll
    for (int r = 0; r < 4; ++r) {
      const int prow = l4 * 4 + r;
#pragma unroll
      for (int n = 0; n < 4; ++n) pb[prow * 72 + n * 16 + l15] = f2b(sv[n][r]);
    }
    const s8v pa0 = *(const s8v*)(pb + l15 * 72 + l4 * 8);
    const s8v pa1 = *(const s8v*)(pb + l15 * 72 + 32 + l4 * 8);
#pragma unroll
    for (int n = 0; n < 4; ++n) {
      s8v vf0 = *(const s8v*)(Vt + (n * 16 + l15) * 72 + l4 * 8);
      s8v vf1 = *(const s8v*)(Vt + (n * 16 + l15) * 72 + 32 + l4 * 8);
      o_acc[n] = MFMA16(pa0, vf0, o_acc[n]);
      o_acc[n] = MFMA16(pa1, vf1, o_acc[n]);
    }
  }

  float invl[4];
#pragma unroll
  for (int r = 0; r < 4; ++r) invl[r] = 1.0f / l_r[r];
  unsigned short* op = out + h * 64;
#pragma unroll
  for (int n = 0; n < 4; ++n)
#pragma unroll
    for (int r = 0; r < 4; ++r) {
      const int row = qb * 64 + wv * 16 + l4 * 4 + r;
      op[(size_t)row * 768 + n * 16 + l15] = f2b(o_acc[n][r] * invl[r]);
    }
}

// ---------------- SwiGLU elementwise: ffn = silu(G) * U, GU = [G|U] ----------------
__global__ __launch_bounds__(256) void silu_mul_k(const unsigned short* __restrict__ GU,
    unsigned short* __restrict__ ffn) {
  const int t = blockIdx.x * 256 + threadIdx.x;  // 4096*256 (8 elems each)
  const int s = t >> 8, j8 = t & 255;
  const s8v g = *(const s8v*)(GU + (size_t)s * 4096 + j8 * 8);
  const s8v u = *(const s8v*)(GU + (size_t)s * 4096 + 2048 + j8 * 8);
  s8v r;
#pragma unroll
  for (int i = 0; i < 8; ++i) {
    const float gv = b2f(g[i]);
    const float uv = b2f(u[i]);
    r[i] = (short)f2b(gv * uv / (1.0f + __expf(-gv)));
  }
  *(s8v*)(ffn + (size_t)s * 2048 + j8 * 8) = r;
}

extern "C" void kernel_launch(void* const* d_in, const int* in_sizes, int n_in,
                              void* d_out, int out_size, void* d_ws, size_t ws_size,
                              hipStream_t stream) {
  const float* x    = (const float*)d_in[0];
  const float* w_q  = (const float*)d_in[1];
  const float* w_k  = (const float*)d_in[2];
  const float* w_v  = (const float*)d_in[3];
  const float* w_o  = (const float*)d_in[4];
  const float* w_g  = (const float*)d_in[5];
  const float* w_u  = (const float*)d_in[6];
  const float* w_d  = (const float*)d_in[7];
  const float* w_n1 = (const float*)d_in[8];
  const float* w_n2 = (const float*)d_in[9];
  (void)in_sizes; (void)n_in; (void)out_size; (void)ws_size;

  char* ws = (char*)d_ws;
  size_t off = 0;
  auto alloc = [&](size_t bytes) { char* p = ws + off; off += (bytes + 255) & ~(size_t)255; return p; };
  unsigned short* wqkvT = (unsigned short*)alloc(2304ull * 768 * 2);
  unsigned short* woT   = (unsigned short*)alloc(768ull * 768 * 2);
  unsigned short* wguT  = (unsigned short*)alloc(4096ull * 768 * 2);
  unsigned short* wdT   = (unsigned short*)alloc(768ull * 2048 * 2);
  float* ct             = (float*)alloc(4096ull * 32 * 4);
  float* st             = (float*)alloc(4096ull * 32 * 4);
  unsigned short* xn    = (unsigned short*)alloc(4096ull * 768 * 2);
  unsigned short* qkv   = (unsigned short*)alloc(4096ull * 2304 * 2);
  unsigned short* attn  = (unsigned short*)alloc(4096ull * 768 * 2);
  float* hbuf           = (float*)alloc(4096ull * 768 * 4);
  unsigned short* ybuf  = (unsigned short*)alloc(4096ull * 768 * 2);
  unsigned short* GU    = (unsigned short*)alloc(4096ull * 4096 * 2);
  unsigned short* ffn   = (unsigned short*)alloc(4096ull * 2048 * 2);

  // weights -> bf16, transposed (Wt[n][k])
  conv_t<<<dim3(24, 24), 256, 0, stream>>>(w_q, wqkvT,                 768, 768);
  conv_t<<<dim3(24, 24), 256, 0, stream>>>(w_k, wqkvT + 768 * 768,     768, 768);
  conv_t<<<dim3(24, 24), 256, 0, stream>>>(w_v, wqkvT + 2 * 768 * 768, 768, 768);
  conv_t<<<dim3(24, 24), 256, 0, stream>>>(w_o, woT,                   768, 768);
  conv_t<<<dim3(64, 24), 256, 0, stream>>>(w_g, wguT,                  768, 2048);
  conv_t<<<dim3(64, 24), 256, 0, stream>>>(w_u, wguT + 2048 * 768,     768, 2048);
  conv_t<<<dim3(24, 64), 256, 0, stream>>>(w_d, wdT,                   2048, 768);
  rope_table_k<<<512, 256, 0, stream>>>(ct, st);

  // xn = rmsnorm(x, w_norm1)
  rmsnorm_k<<<4096, 256, 0, stream>>>(x, w_n1, xn);
  // qkv = xn @ [Wq|Wk|Wv]
  gemm_bt<0><<<dim3(18, 32), 256, 0, stream>>>(xn, wqkvT, qkv, nullptr, nullptr, 768, 2304);
  // rope on q,k in place
  rope_k<<<12288, 256, 0, stream>>>(qkv, ct, st);
  // attention
  flash_k<<<dim3(64, 12), 256, 0, stream>>>(qkv, attn);
  // h = attn @ Wo + x
  gemm_bt<1><<<dim3(6, 32), 256, 0, stream>>>(attn, woT, nullptr, hbuf, x, 768, 768);
  // y = rmsnorm(h, w_norm2)
  rmsnorm_k<<<4096, 256, 0, stream>>>(hbuf, w_n2, ybuf);
  // GU = y @ [Wg|Wu]
  gemm_bt<0><<<dim3(32, 32), 256, 0, stream>>>(ybuf, wguT, GU, nullptr, nullptr, 768, 4096);
  // ffn_in = silu(G) * U
  silu_mul_k<<<4096, 256, 0, stream>>>(GU, ffn);
  // out = ffn_in @ Wd + h
  gemm_bt<1><<<dim3(6, 32), 256, 0, stream>>>(ffn, wdT, nullptr, (float*)d_out, hbuf, 2048, 768);
}

// Round 2
// 318.700 us; speedup vs baseline: 1.2183x; 1.2183x over previous
//
#include <hip/hip_runtime.h>
#include <hip/hip_bf16.h>

typedef __attribute__((ext_vector_type(8))) short s8v;
typedef __attribute__((ext_vector_type(4))) float f4v;

typedef __attribute__((address_space(1))) const void as1_void;
typedef __attribute__((address_space(3))) void as3_void;

__device__ __forceinline__ void gl16(const void* g, void* l) {
  __builtin_amdgcn_global_load_lds((as1_void*)g, (as3_void*)l, 16, 0, 0);
}

__device__ __forceinline__ float b2f(int u) {
  union { float f; unsigned i; } c; c.i = ((unsigned)(u & 0xFFFF)) << 16; return c.f;
}
__device__ __forceinline__ unsigned short f2b(float f) {
  union { float f; unsigned i; } c; c.f = f;
  unsigned r = c.i + 0x7FFFu + ((c.i >> 16) & 1u);
  return (unsigned short)(r >> 16);
}

#define MFMA16(a, b, c) __builtin_amdgcn_mfma_f32_16x16x32_bf16((a), (b), (c), 0, 0, 0)

// ---------------- weight convert + transpose: Wt[n][k] = bf16(W[k][n]) ----------------
__global__ __launch_bounds__(256) void conv_t(const float* __restrict__ W,
    unsigned short* __restrict__ Wt, int K, int N) {
  __shared__ float tile[32][33];
  const int tx = threadIdx.x & 31, ty = threadIdx.x >> 5;  // ty 0..7
  const int bn = blockIdx.x, bk = blockIdx.y;
#pragma unroll
  for (int i = 0; i < 32; i += 8)
    tile[ty + i][tx] = W[(size_t)(bk * 32 + ty + i) * N + bn * 32 + tx];
  __syncthreads();
#pragma unroll
  for (int i = 0; i < 32; i += 8)
    Wt[(size_t)(bn * 32 + ty + i) * K + bk * 32 + tx] = f2b(tile[tx][ty + i]);
}

// ---------------- RMSNorm: fp32 in -> bf16 out, D=768 ----------------
__global__ __launch_bounds__(256) void rmsnorm_k(const float* __restrict__ x,
    const float* __restrict__ w, unsigned short* __restrict__ out) {
  const int row = blockIdx.x, tid = threadIdx.x;
  const float* xr = x + (size_t)row * 768;
  float v0 = xr[tid], v1 = xr[tid + 256], v2 = xr[tid + 512];
  float ss = v0 * v0 + v1 * v1 + v2 * v2;
#pragma unroll
  for (int m = 1; m < 64; m <<= 1) ss += __shfl_xor(ss, m, 64);
  __shared__ float sred[4];
  if ((tid & 63) == 0) sred[tid >> 6] = ss;
  __syncthreads();
  const float tot = sred[0] + sred[1] + sred[2] + sred[3];
  const float rn = rsqrtf(tot * (1.0f / 768.0f) + 1e-6f);
  unsigned short* orow = out + (size_t)row * 768;
  orow[tid]       = f2b(v0 * rn * w[tid]);
  orow[tid + 256] = f2b(v1 * rn * w[tid + 256]);
  orow[tid + 512] = f2b(v2 * rn * w[tid + 512]);
}

// ---------------- RoPE cos/sin table: [4096][32] ----------------
__global__ __launch_bounds__(256) void rope_table_k(float* __restrict__ ct, float* __restrict__ st) {
  const int t = blockIdx.x * 256 + threadIdx.x;  // 4096*32
  const int s = t >> 5, d = t & 31;
  const float inv = powf(10000.0f, -(float)d * (1.0f / 32.0f));
  const float ang = (float)s * inv;
  ct[t] = cosf(ang);
  st[t] = sinf(ang);
}

// ---------------- RoPE in-place on qkv[4096][2304], vectorized 8 pairs/thread ----------------
__global__ __launch_bounds__(256) void rope_k(unsigned short* __restrict__ qkv,
    const float* __restrict__ ct, const float* __restrict__ st) {
  const int t = blockIdx.x * 256 + threadIdx.x;   // 4096*96 threads
  const int s = t / 96, j = t - s * 96;
  const int which = j / 48, jj = j - which * 48;  // 0=q, 1=k
  const int hh = jj >> 2, d8 = (jj & 3) * 8;
  unsigned short* base = qkv + (size_t)s * 2304 + which * 768 + hh * 64 + d8;
  const f4v c0 = *(const f4v*)(ct + s * 32 + d8);
  const f4v c1 = *(const f4v*)(ct + s * 32 + d8 + 4);
  const f4v sn0 = *(const f4v*)(st + s * 32 + d8);
  const f4v sn1 = *(const f4v*)(st + s * 32 + d8 + 4);
  const s8v a = *(const s8v*)(base);
  const s8v b = *(const s8v*)(base + 32);
  s8v ra, rb;
#pragma unroll
  for (int i = 0; i < 8; ++i) {
    const float c  = (i < 4) ? c0[i]  : c1[i - 4];
    const float sn = (i < 4) ? sn0[i] : sn1[i - 4];
    const float av = b2f(a[i]), bv = b2f(b[i]);
    ra[i] = (short)f2b(av * c - bv * sn);
    rb[i] = (short)f2b(bv * c + av * sn);
  }
  *(s8v*)(base) = ra;
  *(s8v*)(base + 32) = rb;
}

// ---------------- GEMM: C[M,N] = A[M,K](bf16) * Bt[N,K](bf16)^T ----------------
template <int EPI>
__global__ __launch_bounds__(256) void gemm_bt(const unsigned short* __restrict__ A,
    const unsigned short* __restrict__ Bt, unsigned short* __restrict__ Cb,
    float* __restrict__ Cf, const float* __restrict__ R, int K, int ldc) {
  __shared__ unsigned short As[128 * 32];
  __shared__ unsigned short Bs[128 * 32];
  const int tid = threadIdx.x;
  const int lane = tid & 63, wid = tid >> 6;
  const int wr = wid >> 1, wc = wid & 1;
  const int l15 = lane & 15, l4 = lane >> 4;
  const int bm = blockIdx.y, bn = blockIdx.x;

  f4v acc[4][4] = {};

  const int o0 = tid * 16, o1 = tid * 16 + 4096;
  const int r0 = o0 >> 6, c0 = o0 & 63;
  const int r1 = o1 >> 6, c1 = o1 & 63;
  const size_t ldab = (size_t)K * 2;
  const char* Abyte = (const char*)A;
  const char* Bbyte = (const char*)Bt;
  const size_t a0 = (size_t)(bm * 128 + r0) * ldab + c0;
  const size_t a1 = (size_t)(bm * 128 + r1) * ldab + c1;
  const size_t b0 = (size_t)(bn * 128 + r0) * ldab + c0;
  const size_t b1 = (size_t)(bn * 128 + r1) * ldab + c1;
  char* AsB = (char*)As;
  char* BsB = (char*)Bs;
  const int uoff = (tid >> 6) << 10;

  for (int k0 = 0; k0 < K; k0 += 32) {
    __syncthreads();
    const size_t kb = (size_t)k0 * 2;
    gl16(Abyte + a0 + kb, AsB + uoff);
    gl16(Abyte + a1 + kb, AsB + uoff + 4096);
    gl16(Bbyte + b0 + kb, BsB + uoff);
    gl16(Bbyte + b1 + kb, BsB + uoff + 4096);
    __syncthreads();
    s8v af[4], bf[4];
#pragma unroll
    for (int m = 0; m < 4; ++m)
      af[m] = *(const s8v*)(AsB + (wr * 64 + m * 16 + l15) * 64 + l4 * 16);
#pragma unroll
    for (int n = 0; n < 4; ++n)
      bf[n] = *(const s8v*)(BsB + (wc * 64 + n * 16 + l15) * 64 + l4 * 16);
#pragma unroll
    for (int m = 0; m < 4; ++m)
#pragma unroll
      for (int n = 0; n < 4; ++n) acc[m][n] = MFMA16(af[m], bf[n], acc[m][n]);
  }

  const int row0 = bm * 128 + wr * 64, col0 = bn * 128 + wc * 64;
#pragma unroll
  for (int m = 0; m < 4; ++m)
#pragma unroll
    for (int n = 0; n < 4; ++n)
#pragma unroll
      for (int r = 0; r < 4; ++r) {
        const int row = row0 + m * 16 + l4 * 4 + r;
        const int col = col0 + n * 16 + l15;
        const float v = acc[m][n][r];
        if (EPI == 0) {
          Cb[(size_t)row * ldc + col] = f2b(v);
        } else {
          Cf[(size_t)row * ldc + col] = v + R[(size_t)row * ldc + col];
        }
      }
}

// ---------------- causal flash attention, balanced pair-half blocks + reg pipeline ----------------
// grid (half=2, p=32, h=12). Block handles 32 rows of qbA=63-p and 32 rows of qbB=p.
__global__ __launch_bounds__(256) void flash_k(const unsigned short* __restrict__ qkv,
    unsigned short* __restrict__ out) {
  const int half = blockIdx.x, p = blockIdx.y, h = blockIdx.z;
  const int qbA = 63 - p, qbB = p;
  const int tid = threadIdx.x;
  const int wv = tid >> 6, lane = tid & 63;
  const int l15 = lane & 15, l4 = lane >> 4;
  const bool low = (wv < 2);
  const bool takeA = low ^ (bool)((p ^ half) & 1);   // per-SIMD load mix
  const int myqb = takeA ? qbA : qbB;
  const int rowbase = myqb * 64 + half * 32 + (wv & 1) * 16;

  __shared__ unsigned short Ks[64 * 72];      // [key][d] padded
  __shared__ unsigned short Vt[64 * 72];      // [d][key] padded (transposed)
  __shared__ unsigned short Pb[4][16 * 72];   // per-wave P staging

  const unsigned short* qp = qkv + h * 64;
  const unsigned short* kp = qkv + 768 + h * 64;
  const unsigned short* vp = qkv + 1536 + h * 64;

  const int qrow = rowbase + l15;
  const s8v qf0 = *(const s8v*)(qp + (size_t)qrow * 2304 + l4 * 8);
  const s8v qf1 = *(const s8v*)(qp + (size_t)qrow * 2304 + 32 + l4 * 8);

  f4v o_acc[4] = {};
  float m_r[4], l_r[4];
#pragma unroll
  for (int r = 0; r < 4; ++r) { m_r[r] = -1e30f; l_r[r] = 0.f; }

  const int krow = tid >> 3, kc = (tid & 7) * 8;   // K staging: rows 0..31 (+32)
  const int vj = tid & 31, vd0 = (tid >> 5) * 8;   // V staging: key-pair, 8 d's

  // prologue: tile 0 into regs
  s8v ka = *(const s8v*)(kp + (size_t)krow * 2304 + kc);
  s8v kb = *(const s8v*)(kp + (size_t)(krow + 32) * 2304 + kc);
  s8v va = *(const s8v*)(vp + (size_t)(2 * vj) * 2304 + vd0);
  s8v vb = *(const s8v*)(vp + (size_t)(2 * vj + 1) * 2304 + vd0);

  for (int t = 0; t <= qbA; ++t) {
    __syncthreads();   // previous tile's LDS readers done
    *(s8v*)(Ks + krow * 72 + kc) = ka;
    *(s8v*)(Ks + (krow + 32) * 72 + kc) = kb;
    {
      unsigned* vtw = (unsigned*)(Vt + (size_t)vd0 * 72 + 2 * vj);
#pragma unroll
      for (int i = 0; i < 8; ++i)
        vtw[i * 36] = ((unsigned)(unsigned short)va[i]) | (((unsigned)(unsigned short)vb[i]) << 16);
    }
    __syncthreads();   // staging visible
    if (t < qbA) {     // prefetch tile t+1 into regs: latency hides under compute
      const size_t k0n = (size_t)(t + 1) * 64;
      ka = *(const s8v*)(kp + (k0n + krow) * 2304 + kc);
      kb = *(const s8v*)(kp + (k0n + krow + 32) * 2304 + kc);
      va = *(const s8v*)(vp + (k0n + 2 * vj) * 2304 + vd0);
      vb = *(const s8v*)(vp + (k0n + 2 * vj + 1) * 2304 + vd0);
    }
    if (t <= myqb) {
      const int k0 = t * 64;
      // scores S[16 q][64 key]
      f4v s_acc[4] = {};
      __builtin_amdgcn_s_setprio(1);
#pragma unroll
      for (int n = 0; n < 4; ++n) {
        s8v kf0 = *(const s8v*)(Ks + (n * 16 + l15) * 72 + l4 * 8);
        s8v kf1 = *(const s8v*)(Ks + (n * 16 + l15) * 72 + 32 + l4 * 8);
        s_acc[n] = MFMA16(qf0, kf0, s_acc[n]);
        s_acc[n] = MFMA16(qf1, kf1, s_acc[n]);
      }
      __builtin_amdgcn_s_setprio(0);

      float sv[4][4];
      float rmax[4] = {-1e30f, -1e30f, -1e30f, -1e30f};
      const bool diag = (t == myqb);
#pragma unroll
      for (int n = 0; n < 4; ++n)
#pragma unroll
        for (int r = 0; r < 4; ++r) {
          float xv = s_acc[n][r] * 0.125f;
          if (diag && (k0 + n * 16 + l15 > rowbase + l4 * 4 + r)) xv = -1e30f;
          sv[n][r] = xv;
          rmax[r] = fmaxf(rmax[r], xv);
        }
#pragma unroll
      for (int mm = 1; mm < 16; mm <<= 1)
#pragma unroll
        for (int r = 0; r < 4; ++r) rmax[r] = fmaxf(rmax[r], __shfl_xor(rmax[r], mm, 64));

      float corr[4], psum[4];
#pragma unroll
      for (int r = 0; r < 4; ++r) {
        const float mn = fmaxf(m_r[r], rmax[r]);
        corr[r] = __expf(m_r[r] - mn);
        m_r[r] = mn;
        psum[r] = 0.f;
      }
#pragma unroll
      for (int n = 0; n < 4; ++n)
#pragma unroll
        for (int r = 0; r < 4; ++r) {
          const float pv = __expf(sv[n][r] - m_r[r]);
          sv[n][r] = pv;
          psum[r] += pv;
        }
#pragma unroll
      for (int mm = 1; mm < 16; mm <<= 1)
#pragma unroll
        for (int r = 0; r < 4; ++r) psum[r] += __shfl_xor(psum[r], mm, 64);
#pragma unroll
      for (int r = 0; r < 4; ++r) l_r[r] = l_r[r] * corr[r] + psum[r];
#pragma unroll
      for (int n = 0; n < 4; ++n)
#pragma unroll
        for (int r = 0; r < 4; ++r) o_acc[n][r] *= corr[r];

      // write P (bf16) to per-wave LDS, re-read as A-fragments
      unsigned short* pb = &Pb[wv][0];
#pragma unroll
      for (int r = 0; r < 4; ++r) {
        const int prow = l4 * 4 + r;
#pragma unroll
        for (int n = 0; n < 4; ++n) pb[prow * 72 + n * 16 + l15] = f2b(sv[n][r]);
      }
      const s8v pa0 = *(const s8v*)(pb + l15 * 72 + l4 * 8);
      const s8v pa1 = *(const s8v*)(pb + l15 * 72 + 32 + l4 * 8);
      __builtin_amdgcn_s_setprio(1);
#pragma unroll
      for (int n = 0; n < 4; ++n) {
        s8v vf0 = *(const s8v*)(Vt + (n * 16 + l15) * 72 + l4 * 8);
        s8v vf1 = *(const s8v*)(Vt + (n * 16 + l15) * 72 + 32 + l4 * 8);
        o_acc[n] = MFMA16(pa0, vf0, o_acc[n]);
        o_acc[n] = MFMA16(pa1, vf1, o_acc[n]);
      }
      __builtin_amdgcn_s_setprio(0);
    }
  }

  float invl[4];
#pragma unroll
  for (int r = 0; r < 4; ++r) invl[r] = 1.0f / l_r[r];
  unsigned short* op = out + h * 64;
#pragma unroll
  for (int n = 0; n < 4; ++n)
#pragma unroll
    for (int r = 0; r < 4; ++r) {
      const int row = rowbase + l4 * 4 + r;
      op[(size_t)row * 768 + n * 16 + l15] = f2b(o_acc[n][r] * invl[r]);
    }
}

// ---------------- SwiGLU elementwise: ffn = silu(G) * U, GU = [G|U] ----------------
__global__ __launch_bounds__(256) void silu_mul_k(const unsigned short* __restrict__ GU,
    unsigned short* __restrict__ ffn) {
  const int t = blockIdx.x * 256 + threadIdx.x;
  const int s = t >> 8, j8 = t & 255;
  const s8v g = *(const s8v*)(GU + (size_t)s * 4096 + j8 * 8);
  const s8v u = *(const s8v*)(GU + (size_t)s * 4096 + 2048 + j8 * 8);
  s8v r;
#pragma unroll
  for (int i = 0; i < 8; ++i) {
    const float gv = b2f(g[i]);
    const float uv = b2f(u[i]);
    r[i] = (short)f2b(gv * uv / (1.0f + __expf(-gv)));
  }
  *(s8v*)(ffn + (size_t)s * 2048 + j8 * 8) = r;
}

extern "C" void kernel_launch(void* const* d_in, const int* in_sizes, int n_in,
                              void* d_out, int out_size, void* d_ws, size_t ws_size,
                              hipStream_t stream) {
  const float* x    = (const float*)d_in[0];
  const float* w_q  = (const float*)d_in[1];
  const float* w_k  = (const float*)d_in[2];
  const float* w_v  = (const float*)d_in[3];
  const float* w_o  = (const float*)d_in[4];
  const float* w_g  = (const float*)d_in[5];
  const float* w_u  = (const float*)d_in[6];
  const float* w_d  = (const float*)d_in[7];
  const float* w_n1 = (const float*)d_in[8];
  const float* w_n2 = (const float*)d_in[9];
  (void)in_sizes; (void)n_in; (void)out_size; (void)ws_size;

  char* ws = (char*)d_ws;
  size_t off = 0;
  auto alloc = [&](size_t bytes) { char* p = ws + off; off += (bytes + 255) & ~(size_t)255; return p; };
  unsigned short* wqkvT = (unsigned short*)alloc(2304ull * 768 * 2);
  unsigned short* woT   = (unsigned short*)alloc(768ull * 768 * 2);
  unsigned short* wguT  = (unsigned short*)alloc(4096ull * 768 * 2);
  unsigned short* wdT   = (unsigned short*)alloc(768ull * 2048 * 2);
  float* ct             = (float*)alloc(4096ull * 32 * 4);
  float* st             = (float*)alloc(4096ull * 32 * 4);
  unsigned short* xn    = (unsigned short*)alloc(4096ull * 768 * 2);
  unsigned short* qkv   = (unsigned short*)alloc(4096ull * 2304 * 2);
  unsigned short* attn  = (unsigned short*)alloc(4096ull * 768 * 2);
  float* hbuf           = (float*)alloc(4096ull * 768 * 4);
  unsigned short* ybuf  = (unsigned short*)alloc(4096ull * 768 * 2);
  unsigned short* GU    = (unsigned short*)alloc(4096ull * 4096 * 2);
  unsigned short* ffn   = (unsigned short*)alloc(4096ull * 2048 * 2);

  conv_t<<<dim3(24, 24), 256, 0, stream>>>(w_q, wqkvT,                 768, 768);
  conv_t<<<dim3(24, 24), 256, 0, stream>>>(w_k, wqkvT + 768 * 768,     768, 768);
  conv_t<<<dim3(24, 24), 256, 0, stream>>>(w_v, wqkvT + 2 * 768 * 768, 768, 768);
  conv_t<<<dim3(24, 24), 256, 0, stream>>>(w_o, woT,                   768, 768);
  conv_t<<<dim3(64, 24), 256, 0, stream>>>(w_g, wguT,                  768, 2048);
  conv_t<<<dim3(64, 24), 256, 0, stream>>>(w_u, wguT + 2048 * 768,     768, 2048);
  conv_t<<<dim3(24, 64), 256, 0, stream>>>(w_d, wdT,                   2048, 768);
  rope_table_k<<<512, 256, 0, stream>>>(ct, st);

  rmsnorm_k<<<4096, 256, 0, stream>>>(x, w_n1, xn);
  gemm_bt<0><<<dim3(18, 32), 256, 0, stream>>>(xn, wqkvT, qkv, nullptr, nullptr, 768, 2304);
  rope_k<<<1536, 256, 0, stream>>>(qkv, ct, st);
  flash_k<<<dim3(2, 32, 12), 256, 0, stream>>>(qkv, attn);
  gemm_bt<1><<<dim3(6, 32), 256, 0, stream>>>(attn, woT, nullptr, hbuf, x, 768, 768);
  rmsnorm_k<<<4096, 256, 0, stream>>>(hbuf, w_n2, ybuf);
  gemm_bt<0><<<dim3(32, 32), 256, 0, stream>>>(ybuf, wguT, GU, nullptr, nullptr, 768, 4096);
  silu_mul_k<<<4096, 256, 0, stream>>>(GU, ffn);
  gemm_bt<1><<<dim3(6, 32), 256, 0, stream>>>(ffn, wdT, nullptr, (float*)d_out, hbuf, 2048, 768);
}

// Round 3
// 278.625 us; speedup vs baseline: 1.3935x; 1.1438x over previous
//
#include <hip/hip_runtime.h>
#include <hip/hip_bf16.h>

typedef __attribute__((ext_vector_type(8))) short s8v;
typedef __attribute__((ext_vector_type(4))) float f4v;

typedef __attribute__((address_space(1))) const void as1_void;
typedef __attribute__((address_space(3))) void as3_void;

__device__ __forceinline__ void gl16(const void* g, void* l) {
  __builtin_amdgcn_global_load_lds((as1_void*)g, (as3_void*)l, 16, 0, 0);
}

__device__ __forceinline__ float b2f(int u) {
  union { float f; unsigned i; } c; c.i = ((unsigned)(u & 0xFFFF)) << 16; return c.f;
}
__device__ __forceinline__ unsigned short f2b(float f) {   // RNE
  union { float f; unsigned i; } c; c.f = f;
  unsigned r = c.i + 0x7FFFu + ((c.i >> 16) & 1u);
  return (unsigned short)(r >> 16);
}
__device__ __forceinline__ unsigned short f2b_fast(float f) {  // 1-op cvt
  unsigned u;
  asm("v_cvt_pk_bf16_f32 %0, %1, %1" : "=v"(u) : "v"(f));
  return (unsigned short)u;
}

#define MFMA16(a, b, c) __builtin_amdgcn_mfma_f32_16x16x32_bf16((a), (b), (c), 0, 0, 0)

// ---------------- fused prep: all weight converts (+gu interleave) + rope tables ----------------
struct Seg { const float* src; unsigned short* dst; int K; int N; int nbn; int nblocks; int mode; };
struct PrepArgs { Seg seg[8]; float* ct; float* st; };

__global__ __launch_bounds__(256) void prep_k(PrepArgs a) {
  int b = blockIdx.x, si = 0;
  while (si < 7 && b >= a.seg[si].nblocks) { b -= a.seg[si].nblocks; ++si; }
  const Seg s = a.seg[si];
  const int tid = threadIdx.x;
  if (s.mode == 3) {               // rope tables [4096][32]
    const int t = b * 256 + tid;
    const int sq = t >> 5, d = t & 31;
    const float inv = powf(10000.0f, -(float)d * (1.0f / 32.0f));
    const float ang = (float)sq * inv;
    a.ct[t] = cosf(ang);
    a.st[t] = sinf(ang);
    return;
  }
  __shared__ float tile[32][33];
  const int tx = tid & 31, ty = tid >> 5;
  const int bn = b % s.nbn, bk = b / s.nbn;
#pragma unroll
  for (int i = 0; i < 32; i += 8)
    tile[ty + i][tx] = s.src[(size_t)(bk * 32 + ty + i) * s.N + bn * 32 + tx];
  __syncthreads();
#pragma unroll
  for (int i = 0; i < 32; i += 8) {
    int row;
    if (s.mode == 0)      row = bn * 32 + ty + i;                 // plain transpose
    else                  row = bn * 64 + (s.mode == 2 ? 32 : 0) + ty + i;  // gu interleave
    s.dst[(size_t)row * s.K + bk * 32 + tx] = f2b(tile[tx][ty + i]);
  }
}

// ---------------- RMSNorm: fp32 in -> bf16 out, D=768 ----------------
__global__ __launch_bounds__(256) void rmsnorm_k(const float* __restrict__ x,
    const float* __restrict__ w, unsigned short* __restrict__ out) {
  const int row = blockIdx.x, tid = threadIdx.x;
  const float* xr = x + (size_t)row * 768;
  float v0 = xr[tid], v1 = xr[tid + 256], v2 = xr[tid + 512];
  float ss = v0 * v0 + v1 * v1 + v2 * v2;
#pragma unroll
  for (int m = 1; m < 64; m <<= 1) ss += __shfl_xor(ss, m, 64);
  __shared__ float sred[4];
  if ((tid & 63) == 0) sred[tid >> 6] = ss;
  __syncthreads();
  const float tot = sred[0] + sred[1] + sred[2] + sred[3];
  const float rn = rsqrtf(tot * (1.0f / 768.0f) + 1e-6f);
  unsigned short* orow = out + (size_t)row * 768;
  orow[tid]       = f2b(v0 * rn * w[tid]);
  orow[tid + 256] = f2b(v1 * rn * w[tid + 256]);
  orow[tid + 512] = f2b(v2 * rn * w[tid + 512]);
}

// ---------------- GEMM: C[M,N] = A[M,K](bf16) * Bt[N,K](bf16)^T ----------------
// EPI 1: fp32 store + fp32 residual add
// EPI 2: bf16 store + RoPE on bn<12 (qkv epilogue), uses ct/st
// EPI 3: silu(gate)*up from 32-interleaved B rows -> bf16, ldc=2048
template <int EPI>
__global__ __launch_bounds__(256) void gemm_bt(const unsigned short* __restrict__ A,
    const unsigned short* __restrict__ Bt, unsigned short* __restrict__ Cb,
    float* __restrict__ Cf, const float* __restrict__ R, int K, int ldc,
    const float* __restrict__ ct, const float* __restrict__ st) {
  __shared__ unsigned short As[128 * 32];
  __shared__ unsigned short Bs[128 * 32];
  const int tid = threadIdx.x;
  const int lane = tid & 63, wid = tid >> 6;
  const int wr = wid >> 1, wc = wid & 1;
  const int l15 = lane & 15, l4 = lane >> 4;
  const int bm = blockIdx.y, bn = blockIdx.x;

  f4v acc[4][4] = {};

  const int o0 = tid * 16, o1 = tid * 16 + 4096;
  const int r0 = o0 >> 6, c0 = o0 & 63;
  const int r1 = o1 >> 6, c1 = o1 & 63;
  const size_t ldab = (size_t)K * 2;
  const char* Abyte = (const char*)A;
  const char* Bbyte = (const char*)Bt;
  const size_t a0 = (size_t)(bm * 128 + r0) * ldab + c0;
  const size_t a1 = (size_t)(bm * 128 + r1) * ldab + c1;
  const size_t b0 = (size_t)(bn * 128 + r0) * ldab + c0;
  const size_t b1 = (size_t)(bn * 128 + r1) * ldab + c1;
  char* AsB = (char*)As;
  char* BsB = (char*)Bs;
  const int uoff = (tid >> 6) << 10;

  for (int k0 = 0; k0 < K; k0 += 32) {
    __syncthreads();
    const size_t kb = (size_t)k0 * 2;
    gl16(Abyte + a0 + kb, AsB + uoff);
    gl16(Abyte + a1 + kb, AsB + uoff + 4096);
    gl16(Bbyte + b0 + kb, BsB + uoff);
    gl16(Bbyte + b1 + kb, BsB + uoff + 4096);
    __syncthreads();
    s8v af[4], bf[4];
#pragma unroll
    for (int m = 0; m < 4; ++m)
      af[m] = *(const s8v*)(AsB + (wr * 64 + m * 16 + l15) * 64 + l4 * 16);
#pragma unroll
    for (int n = 0; n < 4; ++n)
      bf[n] = *(const s8v*)(BsB + (wc * 64 + n * 16 + l15) * 64 + l4 * 16);
#pragma unroll
    for (int m = 0; m < 4; ++m)
#pragma unroll
      for (int n = 0; n < 4; ++n) acc[m][n] = MFMA16(af[m], bf[n], acc[m][n]);
  }

  const int row0 = bm * 128 + wr * 64, col0 = bn * 128 + wc * 64;

  if (EPI == 2 && bn < 12) {       // RoPE in-register: pair (m,n) with (m,n+2)
#pragma unroll
    for (int m = 0; m < 4; ++m)
#pragma unroll
      for (int r = 0; r < 4; ++r) {
        const int row = row0 + m * 16 + l4 * 4 + r;
#pragma unroll
        for (int n = 0; n < 2; ++n) {
          const int d = n * 16 + l15;
          const float c  = ct[row * 32 + d];
          const float sn = st[row * 32 + d];
          const float aa = acc[m][n][r], bb = acc[m][n + 2][r];
          acc[m][n][r]     = aa * c - bb * sn;
          acc[m][n + 2][r] = bb * c + aa * sn;
        }
      }
  }

  if (EPI == 3) {                  // silu(g)*u, g at n<2, u at n+2
    const int colb = (bn * 2 + wc) * 32;
#pragma unroll
    for (int m = 0; m < 4; ++m)
#pragma unroll
      for (int n = 0; n < 2; ++n)
#pragma unroll
        for (int r = 0; r < 4; ++r) {
          const int row = row0 + m * 16 + l4 * 4 + r;
          const float g = acc[m][n][r], u = acc[m][n + 2][r];
          const float val = g * u / (1.0f + __expf(-g));
          Cb[(size_t)row * 2048 + colb + n * 16 + l15] = f2b(val);
        }
    return;
  }

#pragma unroll
  for (int m = 0; m < 4; ++m)
#pragma unroll
    for (int n = 0; n < 4; ++n)
#pragma unroll
      for (int r = 0; r < 4; ++r) {
        const int row = row0 + m * 16 + l4 * 4 + r;
        const int col = col0 + n * 16 + l15;
        const float v = acc[m][n][r];
        if (EPI == 1) {
          Cf[(size_t)row * ldc + col] = v + R[(size_t)row * ldc + col];
        } else {
          Cb[(size_t)row * ldc + col] = f2b(v);
        }
      }
}

// ---------------- causal flash attention: balanced pairs, LDS dbuf, 1 barrier/tile ----------------
__global__ __launch_bounds__(256) void flash_k(const unsigned short* __restrict__ qkv,
    unsigned short* __restrict__ out) {
  const int half = blockIdx.x, p = blockIdx.y, h = blockIdx.z;
  const int qbA = 63 - p, qbB = p;
  const int tid = threadIdx.x;
  const int wv = tid >> 6, lane = tid & 63;
  const int l15 = lane & 15, l4 = lane >> 4;
  const bool low = (wv < 2);
  const bool takeA = low ^ (bool)((p ^ half) & 1);
  const int myqb = takeA ? qbA : qbB;
  const int rowbase = myqb * 64 + half * 32 + (wv & 1) * 16;

  __shared__ unsigned short Ks[2][64 * 72];
  __shared__ unsigned short Vt[2][64 * 72];
  __shared__ unsigned short Pb[4][16 * 72];

  const unsigned short* qp = qkv + h * 64;
  const unsigned short* kp = qkv + 768 + h * 64;
  const unsigned short* vp = qkv + 1536 + h * 64;

  const int qrow = rowbase + l15;
  const s8v qf0 = *(const s8v*)(qp + (size_t)qrow * 2304 + l4 * 8);
  const s8v qf1 = *(const s8v*)(qp + (size_t)qrow * 2304 + 32 + l4 * 8);

  f4v o_acc[4] = {};
  float m_r[4], l_r[4];
#pragma unroll
  for (int r = 0; r < 4; ++r) { m_r[r] = -1e30f; l_r[r] = 0.f; }

  const int krow = tid >> 3, kc = (tid & 7) * 8;
  const int vj = tid & 31, vd0 = (tid >> 5) * 8;

  s8v ka, kb, va, vb;
#define LOADT(T) do { const size_t k0n = (size_t)(T) * 64;                    \
    ka = *(const s8v*)(kp + (k0n + krow) * 2304 + kc);                        \
    kb = *(const s8v*)(kp + (k0n + krow + 32) * 2304 + kc);                   \
    va = *(const s8v*)(vp + (k0n + 2 * vj) * 2304 + vd0);                     \
    vb = *(const s8v*)(vp + (k0n + 2 * vj + 1) * 2304 + vd0); } while (0)
#define WRITET(BUF) do {                                                      \
    *(s8v*)(Ks[BUF] + krow * 72 + kc) = ka;                                   \
    *(s8v*)(Ks[BUF] + (krow + 32) * 72 + kc) = kb;                            \
    unsigned* vtw = (unsigned*)(Vt[BUF] + (size_t)vd0 * 72 + 2 * vj);         \
    _Pragma("unroll")                                                         \
    for (int i = 0; i < 8; ++i)                                               \
      vtw[i * 36] = ((unsigned)(unsigned short)va[i]) |                       \
                    (((unsigned)(unsigned short)vb[i]) << 16); } while (0)

  LOADT(0);
  WRITET(0);
  LOADT(1);           // qbA >= 32 always
  __syncthreads();

  for (int t = 0; t <= qbA; ++t) {
    const int cur = t & 1;
    if (t <= myqb) {
      const int k0 = t * 64;
      f4v s_acc[4] = {};
      __builtin_amdgcn_s_setprio(1);
#pragma unroll
      for (int n = 0; n < 4; ++n) {
        s8v kf0 = *(const s8v*)(Ks[cur] + (n * 16 + l15) * 72 + l4 * 8);
        s8v kf1 = *(const s8v*)(Ks[cur] + (n * 16 + l15) * 72 + 32 + l4 * 8);
        s_acc[n] = MFMA16(qf0, kf0, s_acc[n]);
        s_acc[n] = MFMA16(qf1, kf1, s_acc[n]);
      }
      __builtin_amdgcn_s_setprio(0);

      float sv[4][4];
#pragma unroll
      for (int n = 0; n < 4; ++n)
#pragma unroll
        for (int r = 0; r < 4; ++r) sv[n][r] = s_acc[n][r] * 0.125f;

      if (t == myqb) {             // mask only on diagonal tile (wave-uniform)
#pragma unroll
        for (int n = 0; n < 4; ++n)
#pragma unroll
          for (int r = 0; r < 4; ++r)
            if (k0 + n * 16 + l15 > rowbase + l4 * 4 + r) sv[n][r] = -1e30f;
      }

      float rmax[4] = {-1e30f, -1e30f, -1e30f, -1e30f};
#pragma unroll
      for (int n = 0; n < 4; ++n)
#pragma unroll
        for (int r = 0; r < 4; ++r) rmax[r] = fmaxf(rmax[r], sv[n][r]);
#pragma unroll
      for (int mm = 1; mm < 16; mm <<= 1)
#pragma unroll
        for (int r = 0; r < 4; ++r) rmax[r] = fmaxf(rmax[r], __shfl_xor(rmax[r], mm, 64));

      const int need = (rmax[0] > m_r[0] + 8.f) | (rmax[1] > m_r[1] + 8.f) |
                       (rmax[2] > m_r[2] + 8.f) | (rmax[3] > m_r[3] + 8.f);
      if (__any(need)) {           // defer-max: rescale only when required
#pragma unroll
        for (int r = 0; r < 4; ++r) {
          const float mn = fmaxf(m_r[r], rmax[r]);
          const float corr = __expf(m_r[r] - mn);
          m_r[r] = mn;
          l_r[r] *= corr;
#pragma unroll
          for (int n = 0; n < 4; ++n) o_acc[n][r] *= corr;
        }
      }

      float psum[4] = {0.f, 0.f, 0.f, 0.f};
#pragma unroll
      for (int n = 0; n < 4; ++n)
#pragma unroll
        for (int r = 0; r < 4; ++r) {
          const float pv = __expf(sv[n][r] - m_r[r]);
          sv[n][r] = pv;
          psum[r] += pv;
        }
#pragma unroll
      for (int mm = 1; mm < 16; mm <<= 1)
#pragma unroll
        for (int r = 0; r < 4; ++r) psum[r] += __shfl_xor(psum[r], mm, 64);
#pragma unroll
      for (int r = 0; r < 4; ++r) l_r[r] += psum[r];

      unsigned short* pb = &Pb[wv][0];
#pragma unroll
      for (int r = 0; r < 4; ++r) {
        const int prow = l4 * 4 + r;
#pragma unroll
        for (int n = 0; n < 4; ++n) pb[prow * 72 + n * 16 + l15] = f2b_fast(sv[n][r]);
      }
      const s8v pa0 = *(const s8v*)(pb + l15 * 72 + l4 * 8);
      const s8v pa1 = *(const s8v*)(pb + l15 * 72 + 32 + l4 * 8);
      __builtin_amdgcn_s_setprio(1);
#pragma unroll
      for (int n = 0; n < 4; ++n) {
        s8v vf0 = *(const s8v*)(Vt[cur] + (n * 16 + l15) * 72 + l4 * 8);
        s8v vf1 = *(const s8v*)(Vt[cur] + (n * 16 + l15) * 72 + 32 + l4 * 8);
        o_acc[n] = MFMA16(pa0, vf0, o_acc[n]);
        o_acc[n] = MFMA16(pa1, vf1, o_acc[n]);
      }
      __builtin_amdgcn_s_setprio(0);
    }
    if (t < qbA) {
      WRITET(cur ^ 1);             // tile t+1 regs -> other buffer
      if (t + 2 <= qbA) LOADT(t + 2);
      __syncthreads();             // single barrier per tile
    }
  }

  float invl[4];
#pragma unroll
  for (int r = 0; r < 4; ++r) invl[r] = 1.0f / l_r[r];
  unsigned short* op = out + h * 64;
#pragma unroll
  for (int n = 0; n < 4; ++n)
#pragma unroll
    for (int r = 0; r < 4; ++r) {
      const int row = rowbase + l4 * 4 + r;
      op[(size_t)row * 768 + n * 16 + l15] = f2b(o_acc[n][r] * invl[r]);
    }
#undef LOADT
#undef WRITET
}

extern "C" void kernel_launch(void* const* d_in, const int* in_sizes, int n_in,
                              void* d_out, int out_size, void* d_ws, size_t ws_size,
                              hipStream_t stream) {
  const float* x    = (const float*)d_in[0];
  const float* w_q  = (const float*)d_in[1];
  const float* w_k  = (const float*)d_in[2];
  const float* w_v  = (const float*)d_in[3];
  const float* w_o  = (const float*)d_in[4];
  const float* w_g  = (const float*)d_in[5];
  const float* w_u  = (const float*)d_in[6];
  const float* w_d  = (const float*)d_in[7];
  const float* w_n1 = (const float*)d_in[8];
  const float* w_n2 = (const float*)d_in[9];
  (void)in_sizes; (void)n_in; (void)out_size; (void)ws_size;

  char* ws = (char*)d_ws;
  size_t off = 0;
  auto alloc = [&](size_t bytes) { char* p = ws + off; off += (bytes + 255) & ~(size_t)255; return p; };
  unsigned short* wqkvT = (unsigned short*)alloc(2304ull * 768 * 2);
  unsigned short* woT   = (unsigned short*)alloc(768ull * 768 * 2);
  unsigned short* wguT  = (unsigned short*)alloc(4096ull * 768 * 2);
  unsigned short* wdT   = (unsigned short*)alloc(768ull * 2048 * 2);
  float* ct             = (float*)alloc(4096ull * 32 * 4);
  float* st             = (float*)alloc(4096ull * 32 * 4);
  unsigned short* xn    = (unsigned short*)alloc(4096ull * 768 * 2);
  unsigned short* qkv   = (unsigned short*)alloc(4096ull * 2304 * 2);
  unsigned short* attn  = (unsigned short*)alloc(4096ull * 768 * 2);
  float* hbuf           = (float*)alloc(4096ull * 768 * 4);
  unsigned short* ybuf  = (unsigned short*)alloc(4096ull * 768 * 2);
  unsigned short* ffn   = (unsigned short*)alloc(4096ull * 2048 * 2);

  PrepArgs pa;
  pa.seg[0] = { w_q, wqkvT,                 768,  768, 24,  576, 0 };
  pa.seg[1] = { w_k, wqkvT + 768 * 768,     768,  768, 24,  576, 0 };
  pa.seg[2] = { w_v, wqkvT + 2 * 768 * 768, 768,  768, 24,  576, 0 };
  pa.seg[3] = { w_o, woT,                   768,  768, 24,  576, 0 };
  pa.seg[4] = { w_g, wguT,                  768, 2048, 64, 1536, 1 };
  pa.seg[5] = { w_u, wguT,                  768, 2048, 64, 1536, 2 };
  pa.seg[6] = { w_d, wdT,                  2048,  768, 24, 1536, 0 };
  pa.seg[7] = { nullptr, nullptr, 0, 0, 0, 512, 3 };
  pa.ct = ct; pa.st = st;
  const int prep_blocks = 576 * 4 + 1536 * 3 + 512;   // 7424

  prep_k<<<prep_blocks, 256, 0, stream>>>(pa);
  rmsnorm_k<<<4096, 256, 0, stream>>>(x, w_n1, xn);
  // qkv = xn @ [Wq|Wk|Wv], rope fused in epilogue
  gemm_bt<2><<<dim3(18, 32), 256, 0, stream>>>(xn, wqkvT, qkv, nullptr, nullptr, 768, 2304, ct, st);
  flash_k<<<dim3(2, 32, 12), 256, 0, stream>>>(qkv, attn);
  // h = attn @ Wo + x
  gemm_bt<1><<<dim3(6, 32), 256, 0, stream>>>(attn, woT, nullptr, hbuf, x, 768, 768, nullptr, nullptr);
  rmsnorm_k<<<4096, 256, 0, stream>>>(hbuf, w_n2, ybuf);
  // ffn = silu(y@Wg) * (y@Wu), fused epilogue over interleaved wguT
  gemm_bt<3><<<dim3(32, 32), 256, 0, stream>>>(ybuf, wguT, ffn, nullptr, nullptr, 768, 2048, nullptr, nullptr);
  // out = ffn @ Wd + h
  gemm_bt<1><<<dim3(6, 32), 256, 0, stream>>>(ffn, wdT, nullptr, (float*)d_out, hbuf, 2048, 768, nullptr, nullptr);
}

// Round 4
// 244.259 us; speedup vs baseline: 1.5896x; 1.1407x over previous
//
#include <hip/hip_runtime.h>
#include <hip/hip_bf16.h>

typedef __attribute__((ext_vector_type(8))) short s8v;
typedef __attribute__((ext_vector_type(4))) float f4v;
typedef __attribute__((ext_vector_type(16))) float f16v;
typedef __attribute__((ext_vector_type(4))) unsigned u4v;

typedef __attribute__((address_space(1))) const void as1_void;
typedef __attribute__((address_space(3))) void as3_void;

__device__ __forceinline__ void gl16(const void* g, void* l) {
  __builtin_amdgcn_global_load_lds((as1_void*)g, (as3_void*)l, 16, 0, 0);
}

__device__ __forceinline__ float b2f(int u) {
  union { float f; unsigned i; } c; c.i = ((unsigned)(u & 0xFFFF)) << 16; return c.f;
}
__device__ __forceinline__ unsigned short f2b(float f) {   // RNE
  union { float f; unsigned i; } c; c.f = f;
  unsigned r = c.i + 0x7FFFu + ((c.i >> 16) & 1u);
  return (unsigned short)(r >> 16);
}
__device__ __forceinline__ unsigned pk2(float lo, float hi) {  // 2xbf16 pack
  unsigned u;
  asm("v_cvt_pk_bf16_f32 %0, %1, %2" : "=v"(u) : "v"(lo), "v"(hi));
  return u;
}

#define MFMA16(a, b, c) __builtin_amdgcn_mfma_f32_16x16x32_bf16((a), (b), (c), 0, 0, 0)
#define MFMA32(a, b, c) __builtin_amdgcn_mfma_f32_32x32x16_bf16((a), (b), (c), 0, 0, 0)

// ---------------- fused prep: all weight converts (+gu interleave) + rope tables ----------------
struct Seg { const float* src; unsigned short* dst; int K; int N; int nbn; int nblocks; int mode; };
struct PrepArgs { Seg seg[8]; float* ct; float* st; };

__global__ __launch_bounds__(256) void prep_k(PrepArgs a) {
  int b = blockIdx.x, si = 0;
  while (si < 7 && b >= a.seg[si].nblocks) { b -= a.seg[si].nblocks; ++si; }
  const Seg s = a.seg[si];
  const int tid = threadIdx.x;
  if (s.mode == 3) {               // rope tables [4096][32]
    const int t = b * 256 + tid;
    const int sq = t >> 5, d = t & 31;
    const float inv = powf(10000.0f, -(float)d * (1.0f / 32.0f));
    const float ang = (float)sq * inv;
    a.ct[t] = cosf(ang);
    a.st[t] = sinf(ang);
    return;
  }
  __shared__ float tile[32][33];
  const int tx = tid & 31, ty = tid >> 5;
  const int bn = b % s.nbn, bk = b / s.nbn;
#pragma unroll
  for (int i = 0; i < 32; i += 8)
    tile[ty + i][tx] = s.src[(size_t)(bk * 32 + ty + i) * s.N + bn * 32 + tx];
  __syncthreads();
#pragma unroll
  for (int i = 0; i < 32; i += 8) {
    int row;
    if (s.mode == 0)      row = bn * 32 + ty + i;
    else                  row = bn * 64 + (s.mode == 2 ? 32 : 0) + ty + i;
    s.dst[(size_t)row * s.K + bk * 32 + tx] = f2b(tile[tx][ty + i]);
  }
}

// ---------------- RMSNorm: fp32 in -> bf16 out, D=768 ----------------
__global__ __launch_bounds__(256) void rmsnorm_k(const float* __restrict__ x,
    const float* __restrict__ w, unsigned short* __restrict__ out) {
  const int row = blockIdx.x, tid = threadIdx.x;
  const float* xr = x + (size_t)row * 768;
  float v0 = xr[tid], v1 = xr[tid + 256], v2 = xr[tid + 512];
  float ss = v0 * v0 + v1 * v1 + v2 * v2;
#pragma unroll
  for (int m = 1; m < 64; m <<= 1) ss += __shfl_xor(ss, m, 64);
  __shared__ float sred[4];
  if ((tid & 63) == 0) sred[tid >> 6] = ss;
  __syncthreads();
  const float tot = sred[0] + sred[1] + sred[2] + sred[3];
  const float rn = rsqrtf(tot * (1.0f / 768.0f) + 1e-6f);
  unsigned short* orow = out + (size_t)row * 768;
  orow[tid]       = f2b(v0 * rn * w[tid]);
  orow[tid + 256] = f2b(v1 * rn * w[tid + 256]);
  orow[tid + 512] = f2b(v2 * rn * w[tid + 512]);
}

// ---------------- GEMM: C[M,N] = A[M,K](bf16) * Bt[N,K](bf16)^T ----------------
// EPI 1: fp32 store + fp32 residual add
// EPI 2: bf16 store + RoPE on bn<12 (qkv epilogue)
// EPI 3: silu(gate)*up from 32-interleaved B rows -> bf16, ldc=2048
template <int EPI>
__global__ __launch_bounds__(256) void gemm_bt(const unsigned short* __restrict__ A,
    const unsigned short* __restrict__ Bt, unsigned short* __restrict__ Cb,
    float* __restrict__ Cf, const float* __restrict__ R, int K, int ldc,
    const float* __restrict__ ct, const float* __restrict__ st) {
  __shared__ unsigned short As[128 * 32];
  __shared__ unsigned short Bs[128 * 32];
  const int tid = threadIdx.x;
  const int lane = tid & 63, wid = tid >> 6;
  const int wr = wid >> 1, wc = wid & 1;
  const int l15 = lane & 15, l4 = lane >> 4;
  const int bm = blockIdx.y, bn = blockIdx.x;

  f4v acc[4][4] = {};

  const int o0 = tid * 16, o1 = tid * 16 + 4096;
  const int r0 = o0 >> 6, c0 = o0 & 63;
  const int r1 = o1 >> 6, c1 = o1 & 63;
  const size_t ldab = (size_t)K * 2;
  const char* Abyte = (const char*)A;
  const char* Bbyte = (const char*)Bt;
  const size_t a0 = (size_t)(bm * 128 + r0) * ldab + c0;
  const size_t a1 = (size_t)(bm * 128 + r1) * ldab + c1;
  const size_t b0 = (size_t)(bn * 128 + r0) * ldab + c0;
  const size_t b1 = (size_t)(bn * 128 + r1) * ldab + c1;
  char* AsB = (char*)As;
  char* BsB = (char*)Bs;
  const int uoff = (tid >> 6) << 10;

  for (int k0 = 0; k0 < K; k0 += 32) {
    __syncthreads();
    const size_t kb = (size_t)k0 * 2;
    gl16(Abyte + a0 + kb, AsB + uoff);
    gl16(Abyte + a1 + kb, AsB + uoff + 4096);
    gl16(Bbyte + b0 + kb, BsB + uoff);
    gl16(Bbyte + b1 + kb, BsB + uoff + 4096);
    __syncthreads();
    s8v af[4], bf[4];
#pragma unroll
    for (int m = 0; m < 4; ++m)
      af[m] = *(const s8v*)(AsB + (wr * 64 + m * 16 + l15) * 64 + l4 * 16);
#pragma unroll
    for (int n = 0; n < 4; ++n)
      bf[n] = *(const s8v*)(BsB + (wc * 64 + n * 16 + l15) * 64 + l4 * 16);
#pragma unroll
    for (int m = 0; m < 4; ++m)
#pragma unroll
      for (int n = 0; n < 4; ++n) acc[m][n] = MFMA16(af[m], bf[n], acc[m][n]);
  }

  const int row0 = bm * 128 + wr * 64, col0 = bn * 128 + wc * 64;

  if (EPI == 2 && bn < 12) {       // RoPE in-register: pair (m,n) with (m,n+2)
#pragma unroll
    for (int m = 0; m < 4; ++m)
#pragma unroll
      for (int r = 0; r < 4; ++r) {
        const int row = row0 + m * 16 + l4 * 4 + r;
#pragma unroll
        for (int n = 0; n < 2; ++n) {
          const int d = n * 16 + l15;
          const float c  = ct[row * 32 + d];
          const float sn = st[row * 32 + d];
          const float aa = acc[m][n][r], bb = acc[m][n + 2][r];
          acc[m][n][r]     = aa * c - bb * sn;
          acc[m][n + 2][r] = bb * c + aa * sn;
        }
      }
  }

  if (EPI == 3) {                  // silu(g)*u, g at n<2, u at n+2
    const int colb = (bn * 2 + wc) * 32;
#pragma unroll
    for (int m = 0; m < 4; ++m)
#pragma unroll
      for (int n = 0; n < 2; ++n)
#pragma unroll
        for (int r = 0; r < 4; ++r) {
          const int row = row0 + m * 16 + l4 * 4 + r;
          const float g = acc[m][n][r], u = acc[m][n + 2][r];
          const float val = g * u / (1.0f + __expf(-g));
          Cb[(size_t)row * 2048 + colb + n * 16 + l15] = f2b(val);
        }
    return;
  }

#pragma unroll
  for (int m = 0; m < 4; ++m)
#pragma unroll
    for (int n = 0; n < 4; ++n)
#pragma unroll
      for (int r = 0; r < 4; ++r) {
        const int row = row0 + m * 16 + l4 * 4 + r;
        const int col = col0 + n * 16 + l15;
        const float v = acc[m][n][r];
        if (EPI == 1) {
          Cf[(size_t)row * ldc + col] = v + R[(size_t)row * ldc + col];
        } else {
          Cb[(size_t)row * ldc + col] = f2b(v);
        }
      }
}

// ---------------- causal flash attention: 32x32 swapped-QK, key-parity split ----------------
// grid (kh=2, p=32, h=12). Block: waves 0,2 = qbA rows 0-31/32-63; waves 1,3 = qbB.
// Processes KV tiles t == kh (mod 2); partial (m,l,O^T) written for combine_k.
__global__ __launch_bounds__(256, 3) void flash_k(const unsigned short* __restrict__ qkv,
    float4* __restrict__ Opart, float2* __restrict__ ml) {
  const int kh = blockIdx.x, p = blockIdx.y, h = blockIdx.z;
  const int qbA = 63 - p;
  const int tid = threadIdx.x;
  const int wv = tid >> 6, lane = tid & 63;
  const int l31 = lane & 31, h8 = lane >> 5;
  const int myqb = (wv & 1) ? p : qbA;
  const int qrel = (wv >> 1) * 32 + l31;
  const int q_abs = myqb * 64 + qrel;

  __shared__ unsigned short Ks[2][64 * 72];   // [key][d], 72-padded
  __shared__ unsigned short Vt[2][64 * 72];   // [d][key], 72-padded (transposed)

  const unsigned short* qp = qkv + h * 64;
  const unsigned short* kp = qkv + 768 + h * 64;
  const unsigned short* vp = qkv + 1536 + h * 64;

  s8v qf[4];                                  // Q B-frags, whole kernel
#pragma unroll
  for (int c = 0; c < 4; ++c)
    qf[c] = *(const s8v*)(qp + (size_t)q_abs * 2304 + c * 16 + h8 * 8);

  f16v o0 = {}, o1 = {};                      // O^T acc, d-tiles 0/1
  float m_s = -1e30f, l_s = 0.f;

  const int krow = tid >> 3, kc = (tid & 7) * 8;
  const int vj = tid & 31, vd0 = (tid >> 5) * 8;

  s8v ka, kb, va, vb;
#define LOADT(T) do { const size_t k0n = (size_t)(T) * 64;                    \
    ka = *(const s8v*)(kp + (k0n + krow) * 2304 + kc);                        \
    kb = *(const s8v*)(kp + (k0n + krow + 32) * 2304 + kc);                   \
    va = *(const s8v*)(vp + (k0n + 2 * vj) * 2304 + vd0);                     \
    vb = *(const s8v*)(vp + (k0n + 2 * vj + 1) * 2304 + vd0); } while (0)
#define WRITET(BUF) do {                                                      \
    *(s8v*)(Ks[BUF] + krow * 72 + kc) = ka;                                   \
    *(s8v*)(Ks[BUF] + (krow + 32) * 72 + kc) = kb;                            \
    unsigned* vtw = (unsigned*)(Vt[BUF] + (size_t)vd0 * 72 + 2 * vj);         \
    _Pragma("unroll")                                                         \
    for (int i = 0; i < 8; ++i)                                               \
      vtw[i * 36] = ((unsigned)(unsigned short)va[i]) |                       \
                    (((unsigned)(unsigned short)vb[i]) << 16); } while (0)

  LOADT(kh);
  WRITET(0);
  if (kh + 2 <= qbA) LOADT(kh + 2);
  __syncthreads();

  for (int t = kh; t <= qbA; t += 2) {
    const int cur = (t >> 1) & 1;
    if (t <= myqb) {
      // S^T[key][q] = K * Q^T (swapped): lane q=l31, 32 keys split by h8
      f16v s0 = {}, s1 = {};
      __builtin_amdgcn_s_setprio(1);
#pragma unroll
      for (int c = 0; c < 4; ++c) {
        const s8v kf0 = *(const s8v*)(Ks[cur] + l31 * 72 + c * 16 + h8 * 8);
        const s8v kf1 = *(const s8v*)(Ks[cur] + (32 + l31) * 72 + c * 16 + h8 * 8);
        s0 = MFMA32(kf0, qf[c], s0);
        s1 = MFMA32(kf1, qf[c], s1);
      }
      __builtin_amdgcn_s_setprio(0);
#pragma unroll
      for (int r = 0; r < 16; ++r) { s0[r] *= 0.125f; s1[r] *= 0.125f; }
      if (t == myqb) {                       // diagonal tile: causal mask
#pragma unroll
        for (int r = 0; r < 16; ++r) {
          const int koff = (r & 3) + 8 * (r >> 2) + 4 * h8;
          if (koff > qrel) s0[r] = -1e30f;
          if (koff + 32 > qrel) s1[r] = -1e30f;
        }
      }
      // row max: in-lane tree + one cross-half shuffle
      float red[8];
#pragma unroll
      for (int i = 0; i < 8; ++i)
        red[i] = fmaxf(fmaxf(s0[i], s0[i + 8]), fmaxf(s1[i], s1[i + 8]));
#pragma unroll
      for (int i = 0; i < 4; ++i) red[i] = fmaxf(red[i], red[i + 4]);
      float mloc = fmaxf(fmaxf(red[0], red[1]), fmaxf(red[2], red[3]));
      mloc = fmaxf(mloc, __shfl_xor(mloc, 32));
      if (__any(mloc > m_s + 8.f)) {         // defer-max
        const float mn = fmaxf(m_s, mloc);
        const float corr = __expf(m_s - mn);
        m_s = mn; l_s *= corr;
#pragma unroll
        for (int r = 0; r < 16; ++r) { o0[r] *= corr; o1[r] *= corr; }
      }
#pragma unroll
      for (int r = 0; r < 16; ++r) {
        s0[r] = __expf(s0[r] - m_s);
        s1[r] = __expf(s1[r] - m_s);
      }
      float sm[8];
#pragma unroll
      for (int i = 0; i < 8; ++i) sm[i] = (s0[i] + s0[i + 8]) + (s1[i] + s1[i + 8]);
#pragma unroll
      for (int i = 0; i < 4; ++i) sm[i] += sm[i + 4];
      float ps = (sm[0] + sm[1]) + (sm[2] + sm[3]);
      ps += __shfl_xor(ps, 32);
      l_s += ps;

      // pack P to bf16 pairs; cross-half redistribute into PV B-frags
      unsigned pk0[8], pk1[8];
#pragma unroll
      for (int g = 0; g < 4; ++g)
#pragma unroll
        for (int j = 0; j < 2; ++j) {
          pk0[g * 2 + j] = pk2(s0[g * 4 + 2 * j], s0[g * 4 + 2 * j + 1]);
          pk1[g * 2 + j] = pk2(s1[g * 4 + 2 * j], s1[g * 4 + 2 * j + 1]);
        }
      __builtin_amdgcn_s_setprio(1);
#pragma unroll
      for (int c = 0; c < 4; ++c) {
        const int g0 = (c & 1) * 2, g1 = g0 + 1;
        const unsigned pA0 = (c & 2) ? pk1[g0 * 2 + 0] : pk0[g0 * 2 + 0];
        const unsigned pA1 = (c & 2) ? pk1[g0 * 2 + 1] : pk0[g0 * 2 + 1];
        const unsigned pB0 = (c & 2) ? pk1[g1 * 2 + 0] : pk0[g1 * 2 + 0];
        const unsigned pB1 = (c & 2) ? pk1[g1 * 2 + 1] : pk0[g1 * 2 + 1];
        const unsigned t00 = __shfl_xor((int)pA0, 32);
        const unsigned t01 = __shfl_xor((int)pA1, 32);
        const unsigned t10 = __shfl_xor((int)pB0, 32);
        const unsigned t11 = __shfl_xor((int)pB1, 32);
        union { u4v u; s8v s; } pf;
        pf.u[0] = h8 ? t10 : pA0;
        pf.u[1] = h8 ? t11 : pA1;
        pf.u[2] = h8 ? pB0 : t00;
        pf.u[3] = h8 ? pB1 : t01;
        const s8v vf0 = *(const s8v*)(Vt[cur] + l31 * 72 + c * 16 + h8 * 8);
        const s8v vf1 = *(const s8v*)(Vt[cur] + (32 + l31) * 72 + c * 16 + h8 * 8);
        o0 = MFMA32(vf0, pf.s, o0);
        o1 = MFMA32(vf1, pf.s, o1);
      }
      __builtin_amdgcn_s_setprio(0);
    }
    if (t + 2 <= qbA) {
      WRITET(cur ^ 1);
      if (t + 4 <= qbA) LOADT(t + 4);
      __syncthreads();
    }
  }

  // write partials: O^T unnormalized, grouped float4 [kh][h][dgrp][q]
  const size_t obase = (size_t)kh * 12 * 16 * 4096;
#pragma unroll
  for (int g = 0; g < 4; ++g) {
    const float4 v0 = make_float4(o0[g * 4], o0[g * 4 + 1], o0[g * 4 + 2], o0[g * 4 + 3]);
    const float4 v1 = make_float4(o1[g * 4], o1[g * 4 + 1], o1[g * 4 + 2], o1[g * 4 + 3]);
    const int dg0 = 2 * g + h8;
    const int dg1 = 8 + 2 * g + h8;
    Opart[obase + ((size_t)h * 16 + dg0) * 4096 + q_abs] = v0;
    Opart[obase + ((size_t)h * 16 + dg1) * 4096 + q_abs] = v1;
  }
  if (h8 == 0)
    ml[(size_t)kh * 12 * 4096 + (size_t)h * 4096 + q_abs] = make_float2(m_s, l_s);
#undef LOADT
#undef WRITET
}

// ---------------- combine the two key-parity halves -> attn bf16 [q][768] ----------------
__global__ __launch_bounds__(256) void combine_k(const float4* __restrict__ Opart,
    const float2* __restrict__ ml, unsigned short* __restrict__ out) {
  const int t = blockIdx.x * 256 + threadIdx.x;   // 12*4096*64
  const int d = t & 63;
  const int q = (t >> 6) & 4095;
  const int h = t >> 18;
  const float2 e0 = ml[h * 4096 + q];
  const float2 e1 = ml[12 * 4096 + h * 4096 + q];
  const float mx = fmaxf(e0.x, e1.x);
  const float w0 = __expf(e0.x - mx), w1 = __expf(e1.x - mx);
  const float inv = 1.0f / (w0 * e0.y + w1 * e1.y);
  const int dgrp = (d >> 5) * 8 + ((d >> 3) & 3) * 2 + ((d >> 2) & 1);
  const size_t fidx = ((((size_t)h * 16 + dgrp) * 4096 + q) << 2) + (d & 3);
  const float* O0 = (const float*)Opart;
  const float* O1 = O0 + (size_t)12 * 16 * 4096 * 4;
  const float v = (w0 * O0[fidx] + w1 * O1[fidx]) * inv;
  out[(size_t)q * 768 + h * 64 + d] = f2b(v);
}

extern "C" void kernel_launch(void* const* d_in, const int* in_sizes, int n_in,
                              void* d_out, int out_size, void* d_ws, size_t ws_size,
                              hipStream_t stream) {
  const float* x    = (const float*)d_in[0];
  const float* w_q  = (const float*)d_in[1];
  const float* w_k  = (const float*)d_in[2];
  const float* w_v  = (const float*)d_in[3];
  const float* w_o  = (const float*)d_in[4];
  const float* w_g  = (const float*)d_in[5];
  const float* w_u  = (const float*)d_in[6];
  const float* w_d  = (const float*)d_in[7];
  const float* w_n1 = (const float*)d_in[8];
  const float* w_n2 = (const float*)d_in[9];
  (void)in_sizes; (void)n_in; (void)out_size; (void)ws_size;

  char* ws = (char*)d_ws;
  size_t off = 0;
  auto alloc = [&](size_t bytes) { char* p = ws + off; off += (bytes + 255) & ~(size_t)255; return p; };
  unsigned short* wqkvT = (unsigned short*)alloc(2304ull * 768 * 2);
  unsigned short* woT   = (unsigned short*)alloc(768ull * 768 * 2);
  unsigned short* wguT  = (unsigned short*)alloc(4096ull * 768 * 2);
  unsigned short* wdT   = (unsigned short*)alloc(768ull * 2048 * 2);
  float* ct             = (float*)alloc(4096ull * 32 * 4);
  float* st             = (float*)alloc(4096ull * 32 * 4);
  unsigned short* xn    = (unsigned short*)alloc(4096ull * 768 * 2);
  unsigned short* qkv   = (unsigned short*)alloc(4096ull * 2304 * 2);
  unsigned short* attn  = (unsigned short*)alloc(4096ull * 768 * 2);
  float* hbuf           = (float*)alloc(4096ull * 768 * 4);
  unsigned short* ybuf  = (unsigned short*)alloc(4096ull * 768 * 2);
  unsigned short* ffn   = (unsigned short*)alloc(4096ull * 2048 * 2);
  float4* Opart         = (float4*)alloc(2ull * 12 * 16 * 4096 * 16);
  float2* mlb           = (float2*)alloc(2ull * 12 * 4096 * 8);

  PrepArgs pa;
  pa.seg[0] = { w_q, wqkvT,                 768,  768, 24,  576, 0 };
  pa.seg[1] = { w_k, wqkvT + 768 * 768,     768,  768, 24,  576, 0 };
  pa.seg[2] = { w_v, wqkvT + 2 * 768 * 768, 768,  768, 24,  576, 0 };
  pa.seg[3] = { w_o, woT,                   768,  768, 24,  576, 0 };
  pa.seg[4] = { w_g, wguT,                  768, 2048, 64, 1536, 1 };
  pa.seg[5] = { w_u, wguT,                  768, 2048, 64, 1536, 2 };
  pa.seg[6] = { w_d, wdT,                  2048,  768, 24, 1536, 0 };
  pa.seg[7] = { nullptr, nullptr, 0, 0, 0, 512, 3 };
  pa.ct = ct; pa.st = st;
  const int prep_blocks = 576 * 4 + 1536 * 3 + 512;   // 7424

  prep_k<<<prep_blocks, 256, 0, stream>>>(pa);
  rmsnorm_k<<<4096, 256, 0, stream>>>(x, w_n1, xn);
  gemm_bt<2><<<dim3(18, 32), 256, 0, stream>>>(xn, wqkvT, qkv, nullptr, nullptr, 768, 2304, ct, st);
  flash_k<<<dim3(2, 32, 12), 256, 0, stream>>>(qkv, Opart, mlb);
  combine_k<<<12288, 256, 0, stream>>>(Opart, mlb, attn);
  gemm_bt<1><<<dim3(6, 32), 256, 0, stream>>>(attn, woT, nullptr, hbuf, x, 768, 768, nullptr, nullptr);
  rmsnorm_k<<<4096, 256, 0, stream>>>(hbuf, w_n2, ybuf);
  gemm_bt<3><<<dim3(32, 32), 256, 0, stream>>>(ybuf, wguT, ffn, nullptr, nullptr, 768, 2048, nullptr, nullptr);
  gemm_bt<1><<<dim3(6, 32), 256, 0, stream>>>(ffn, wdT, nullptr, (float*)d_out, hbuf, 2048, 768, nullptr, nullptr);
}

// Round 5
// 236.762 us; speedup vs baseline: 1.6399x; 1.0317x over previous
//
#include <hip/hip_runtime.h>
#include <hip/hip_bf16.h>

typedef __attribute__((ext_vector_type(8))) short s8v;
typedef __attribute__((ext_vector_type(4))) float f4v;
typedef __attribute__((ext_vector_type(16))) float f16v;
typedef __attribute__((ext_vector_type(4))) unsigned u4v;

typedef __attribute__((address_space(1))) const void as1_void;
typedef __attribute__((address_space(3))) void as3_void;

__device__ __forceinline__ void gl16(const void* g, void* l) {
  __builtin_amdgcn_global_load_lds((as1_void*)g, (as3_void*)l, 16, 0, 0);
}

__device__ __forceinline__ float b2f(int u) {
  union { float f; unsigned i; } c; c.i = ((unsigned)(u & 0xFFFF)) << 16; return c.f;
}
__device__ __forceinline__ unsigned short f2b(float f) {   // RNE
  union { float f; unsigned i; } c; c.f = f;
  unsigned r = c.i + 0x7FFFu + ((c.i >> 16) & 1u);
  return (unsigned short)(r >> 16);
}
__device__ __forceinline__ unsigned pk2(float lo, float hi) {  // 2xbf16 pack
  unsigned u;
  asm("v_cvt_pk_bf16_f32 %0, %1, %2" : "=v"(u) : "v"(lo), "v"(hi));
  return u;
}

#define MFMA16(a, b, c) __builtin_amdgcn_mfma_f32_16x16x32_bf16((a), (b), (c), 0, 0, 0)
#define MFMA32(a, b, c) __builtin_amdgcn_mfma_f32_32x32x16_bf16((a), (b), (c), 0, 0, 0)

// ---------------- fused prep: all weight converts (+gu interleave) + rope tables ----------------
struct Seg { const float* src; unsigned short* dst; int K; int N; int nbn; int nblocks; int mode; };
struct PrepArgs { Seg seg[8]; float* ct; float* st; };

__global__ __launch_bounds__(256) void prep_k(PrepArgs a) {
  int b = blockIdx.x, si = 0;
  while (si < 7 && b >= a.seg[si].nblocks) { b -= a.seg[si].nblocks; ++si; }
  const Seg s = a.seg[si];
  const int tid = threadIdx.x;
  if (s.mode == 3) {               // rope tables [4096][32]
    const int t = b * 256 + tid;
    const int sq = t >> 5, d = t & 31;
    const float inv = powf(10000.0f, -(float)d * (1.0f / 32.0f));
    const float ang = (float)sq * inv;
    a.ct[t] = cosf(ang);
    a.st[t] = sinf(ang);
    return;
  }
  __shared__ float tile[32][33];
  const int tx = tid & 31, ty = tid >> 5;
  const int bn = b % s.nbn, bk = b / s.nbn;
#pragma unroll
  for (int i = 0; i < 32; i += 8)
    tile[ty + i][tx] = s.src[(size_t)(bk * 32 + ty + i) * s.N + bn * 32 + tx];
  __syncthreads();
#pragma unroll
  for (int i = 0; i < 32; i += 8) {
    int row;
    if (s.mode == 0)      row = bn * 32 + ty + i;
    else                  row = bn * 64 + (s.mode == 2 ? 32 : 0) + ty + i;
    s.dst[(size_t)row * s.K + bk * 32 + tx] = f2b(tile[tx][ty + i]);
  }
}

// ---------------- RMSNorm: fp32 in -> bf16 out, D=768 ----------------
__global__ __launch_bounds__(256) void rmsnorm_k(const float* __restrict__ x,
    const float* __restrict__ w, unsigned short* __restrict__ out) {
  const int row = blockIdx.x, tid = threadIdx.x;
  const float* xr = x + (size_t)row * 768;
  float v0 = xr[tid], v1 = xr[tid + 256], v2 = xr[tid + 512];
  float ss = v0 * v0 + v1 * v1 + v2 * v2;
#pragma unroll
  for (int m = 1; m < 64; m <<= 1) ss += __shfl_xor(ss, m, 64);
  __shared__ float sred[4];
  if ((tid & 63) == 0) sred[tid >> 6] = ss;
  __syncthreads();
  const float tot = sred[0] + sred[1] + sred[2] + sred[3];
  const float rn = rsqrtf(tot * (1.0f / 768.0f) + 1e-6f);
  unsigned short* orow = out + (size_t)row * 768;
  orow[tid]       = f2b(v0 * rn * w[tid]);
  orow[tid + 256] = f2b(v1 * rn * w[tid + 256]);
  orow[tid + 512] = f2b(v2 * rn * w[tid + 512]);
}

// ---------------- GEMM: C[M,N] = A[M,K](bf16) * Bt[N,K](bf16)^T, 2-phase LDS dbuf ----------------
// EPI 1: fp32 store + fp32 residual add
// EPI 2: bf16 store + RoPE on bn<12 (qkv epilogue)
// EPI 3: silu(gate)*up from 32-interleaved B rows -> bf16, ldc=2048
template <int EPI, int BN>
__global__ __launch_bounds__(256) void gemm_bt(const unsigned short* __restrict__ A,
    const unsigned short* __restrict__ Bt, unsigned short* __restrict__ Cb,
    float* __restrict__ Cf, const float* __restrict__ R, int K, int ldc,
    const float* __restrict__ ct, const float* __restrict__ st) {
  constexpr int ABYTES = 128 * 32 * 2;
  constexpr int BBYTES = BN * 32 * 2;
  constexpr int MR = (BN == 128) ? 4 : 2;
  __shared__ unsigned short As[2 * 128 * 32];
  __shared__ unsigned short Bs[2 * BN * 32];
  const int tid = threadIdx.x;
  const int lane = tid & 63, wid = tid >> 6;
  const int wrow = (BN == 128) ? (wid >> 1) * 64 : wid * 32;
  const int wcol = (BN == 128) ? (wid & 1) * 64 : 0;
  const int l15 = lane & 15, l4 = lane >> 4;
  const int bm = blockIdx.y, bn = blockIdx.x;

  f4v acc[MR][4] = {};

  const int o0 = tid * 16, o1 = tid * 16 + 4096;
  const int r0 = o0 >> 6, c0 = o0 & 63;
  const int r1 = o1 >> 6, c1 = o1 & 63;
  const size_t ldab = (size_t)K * 2;
  const char* Abyte = (const char*)A;
  const char* Bbyte = (const char*)Bt;
  const size_t a0 = (size_t)(bm * 128 + r0) * ldab + c0;
  const size_t a1 = (size_t)(bm * 128 + r1) * ldab + c1;
  const size_t b0 = (size_t)(bn * BN + r0) * ldab + c0;
  const size_t b1 = (size_t)(bn * BN + r1) * ldab + c1;   // used only when BN==128
  char* AsB = (char*)As;
  char* BsB = (char*)Bs;
  const int uoff = wid << 10;

  const int NI = K >> 5;
  // prologue: stage K-step 0 into buffer 0
  gl16(Abyte + a0, AsB + uoff);
  gl16(Abyte + a1, AsB + uoff + 4096);
  gl16(Bbyte + b0, BsB + uoff);
  if (BN == 128) gl16(Bbyte + b1, BsB + uoff + 4096);
  asm volatile("s_waitcnt vmcnt(0)" ::: "memory");
  __syncthreads();

  for (int i = 0; i < NI; ++i) {
    const int bsel = i & 1;
    char* Ar = AsB + bsel * ABYTES;
    char* Br = BsB + bsel * BBYTES;
    if (i + 1 < NI) {              // stage next K-step into other buffer (in flight over MFMA)
      const size_t kb = (size_t)(i + 1) * 64;
      char* Aw = AsB + (bsel ^ 1) * ABYTES;
      char* Bw = BsB + (bsel ^ 1) * BBYTES;
      gl16(Abyte + a0 + kb, Aw + uoff);
      gl16(Abyte + a1 + kb, Aw + uoff + 4096);
      gl16(Bbyte + b0 + kb, Bw + uoff);
      if (BN == 128) gl16(Bbyte + b1 + kb, Bw + uoff + 4096);
    }
    s8v af[MR], bf[4];
#pragma unroll
    for (int m = 0; m < MR; ++m)
      af[m] = *(const s8v*)(Ar + (wrow + m * 16 + l15) * 64 + l4 * 16);
#pragma unroll
    for (int n = 0; n < 4; ++n)
      bf[n] = *(const s8v*)(Br + (wcol + n * 16 + l15) * 64 + l4 * 16);
    __builtin_amdgcn_s_setprio(1);
#pragma unroll
    for (int m = 0; m < MR; ++m)
#pragma unroll
      for (int n = 0; n < 4; ++n) acc[m][n] = MFMA16(af[m], bf[n], acc[m][n]);
    __builtin_amdgcn_s_setprio(0);
    asm volatile("s_waitcnt vmcnt(0)" ::: "memory");
    __syncthreads();
  }

  const int row0 = bm * 128 + wrow;
  const int col0 = bn * BN + wcol;

  if (EPI == 2 && bn < 12) {       // RoPE in-register: pair (m,n) with (m,n+2)
#pragma unroll
    for (int m = 0; m < MR; ++m)
#pragma unroll
      for (int r = 0; r < 4; ++r) {
        const int row = row0 + m * 16 + l4 * 4 + r;
#pragma unroll
        for (int n = 0; n < 2; ++n) {
          const int d = n * 16 + l15;
          const float c  = ct[row * 32 + d];
          const float sn = st[row * 32 + d];
          const float aa = acc[m][n][r], bb = acc[m][n + 2][r];
          acc[m][n][r]     = aa * c - bb * sn;
          acc[m][n + 2][r] = bb * c + aa * sn;
        }
      }
  }

  if (EPI == 3) {                  // silu(g)*u, g at n<2, u at n+2
    const int wcx = wcol >> 6;
    const int colb = (bn * 2 + wcx) * 32;
#pragma unroll
    for (int m = 0; m < MR; ++m)
#pragma unroll
      for (int n = 0; n < 2; ++n)
#pragma unroll
        for (int r = 0; r < 4; ++r) {
          const int row = row0 + m * 16 + l4 * 4 + r;
          const float g = acc[m][n][r], u = acc[m][n + 2][r];
          const float val = g * u / (1.0f + __expf(-g));
          Cb[(size_t)row * 2048 + colb + n * 16 + l15] = f2b(val);
        }
    return;
  }

#pragma unroll
  for (int m = 0; m < MR; ++m)
#pragma unroll
    for (int n = 0; n < 4; ++n)
#pragma unroll
      for (int r = 0; r < 4; ++r) {
        const int row = row0 + m * 16 + l4 * 4 + r;
        const int col = col0 + n * 16 + l15;
        const float v = acc[m][n][r];
        if (EPI == 1) {
          Cf[(size_t)row * ldc + col] = v + R[(size_t)row * ldc + col];
        } else {
          Cb[(size_t)row * ldc + col] = f2b(v);
        }
      }
}

// ---------------- causal flash attention: 32x32 swapped-QK, 128-row blocks, key-parity ----------------
// grid (kh=2, 32, h=12). Block: 4 waves x 32 rows of one 128-row q-super-block (qs = 31-by).
// Tiles t == kh (mod 2), t <= 2qs+kh. All waves busy every tile (+-1).
__global__ __launch_bounds__(256, 4) void flash_k(const unsigned short* __restrict__ qkv,
    float4* __restrict__ Opart, float2* __restrict__ ml) {
  const int kh = blockIdx.x;
  const int qs = 31 - (int)blockIdx.y;   // long blocks first
  const int h = blockIdx.z;
  const int tid = threadIdx.x;
  const int wv = tid >> 6, lane = tid & 63;
  const int l31 = lane & 31, h8 = lane >> 5;
  const int dt = 2 * qs + (wv >> 1);     // this wave's diagonal tile
  const int qrel = wv * 32 + l31;
  const int q_abs = qs * 128 + qrel;
  const int qm = ((wv & 1) << 5) + l31;  // q offset within diagonal tile
  const int T = 2 * qs + kh;             // last tile with parity kh

  __shared__ unsigned short Ks[2][64 * 72];   // [key][d], 72-padded
  __shared__ unsigned short Vt[2][64 * 72];   // [d][key], 72-padded (transposed)

  const unsigned short* qp = qkv + h * 64;
  const unsigned short* kp = qkv + 768 + h * 64;
  const unsigned short* vp = qkv + 1536 + h * 64;

  s8v qf[4];
#pragma unroll
  for (int c = 0; c < 4; ++c)
    qf[c] = *(const s8v*)(qp + (size_t)q_abs * 2304 + c * 16 + h8 * 8);

  f16v o0 = {}, o1 = {};
  float m_s = -1e30f, l_s = 0.f;

  const int krow = tid >> 3, kc = (tid & 7) * 8;
  const int vj = tid & 31, vd0 = (tid >> 5) * 8;

  s8v ka, kb, va, vb;
#define LOADT(TT) do { const size_t k0n = (size_t)(TT) * 64;                  \
    ka = *(const s8v*)(kp + (k0n + krow) * 2304 + kc);                        \
    kb = *(const s8v*)(kp + (k0n + krow + 32) * 2304 + kc);                   \
    va = *(const s8v*)(vp + (k0n + 2 * vj) * 2304 + vd0);                     \
    vb = *(const s8v*)(vp + (k0n + 2 * vj + 1) * 2304 + vd0); } while (0)
#define WRITET(BUF) do {                                                      \
    *(s8v*)(Ks[BUF] + krow * 72 + kc) = ka;                                   \
    *(s8v*)(Ks[BUF] + (krow + 32) * 72 + kc) = kb;                            \
    unsigned* vtw = (unsigned*)(Vt[BUF] + (size_t)vd0 * 72 + 2 * vj);         \
    _Pragma("unroll")                                                         \
    for (int i = 0; i < 8; ++i)                                               \
      vtw[i * 36] = ((unsigned)(unsigned short)va[i]) |                       \
                    (((unsigned)(unsigned short)vb[i]) << 16); } while (0)

  LOADT(kh);
  WRITET(0);
  if (kh + 2 <= T) LOADT(kh + 2);
  __syncthreads();

  for (int t = kh; t <= T; t += 2) {
    const int cur = (t >> 1) & 1;
    if (t <= dt) {
      // S^T[key][q] = K * Q^T (swapped): lane q=l31, 32 keys split by h8
      f16v s0 = {}, s1 = {};
      __builtin_amdgcn_s_setprio(1);
#pragma unroll
      for (int c = 0; c < 4; ++c) {
        const s8v kf0 = *(const s8v*)(Ks[cur] + l31 * 72 + c * 16 + h8 * 8);
        const s8v kf1 = *(const s8v*)(Ks[cur] + (32 + l31) * 72 + c * 16 + h8 * 8);
        s0 = MFMA32(kf0, qf[c], s0);
        s1 = MFMA32(kf1, qf[c], s1);
      }
      __builtin_amdgcn_s_setprio(0);
#pragma unroll
      for (int r = 0; r < 16; ++r) { s0[r] *= 0.125f; s1[r] *= 0.125f; }
      if (t == dt) {                        // diagonal tile: causal mask
#pragma unroll
        for (int r = 0; r < 16; ++r) {
          const int koff = (r & 3) + 8 * (r >> 2) + 4 * h8;
          if (koff > qm) s0[r] = -1e30f;
          if (koff + 32 > qm) s1[r] = -1e30f;
        }
      }
      float red[8];
#pragma unroll
      for (int i = 0; i < 8; ++i)
        red[i] = fmaxf(fmaxf(s0[i], s0[i + 8]), fmaxf(s1[i], s1[i + 8]));
#pragma unroll
      for (int i = 0; i < 4; ++i) red[i] = fmaxf(red[i], red[i + 4]);
      float mloc = fmaxf(fmaxf(red[0], red[1]), fmaxf(red[2], red[3]));
      mloc = fmaxf(mloc, __shfl_xor(mloc, 32));
      if (__any(mloc > m_s + 8.f)) {        // defer-max
        const float mn = fmaxf(m_s, mloc);
        const float corr = __expf(m_s - mn);
        m_s = mn; l_s *= corr;
#pragma unroll
        for (int r = 0; r < 16; ++r) { o0[r] *= corr; o1[r] *= corr; }
      }
#pragma unroll
      for (int r = 0; r < 16; ++r) {
        s0[r] = __expf(s0[r] - m_s);
        s1[r] = __expf(s1[r] - m_s);
      }
      float sm[8];
#pragma unroll
      for (int i = 0; i < 8; ++i) sm[i] = (s0[i] + s0[i + 8]) + (s1[i] + s1[i + 8]);
#pragma unroll
      for (int i = 0; i < 4; ++i) sm[i] += sm[i + 4];
      float ps = (sm[0] + sm[1]) + (sm[2] + sm[3]);
      ps += __shfl_xor(ps, 32);
      l_s += ps;

      unsigned pk0[8], pk1[8];
#pragma unroll
      for (int g = 0; g < 4; ++g)
#pragma unroll
        for (int j = 0; j < 2; ++j) {
          pk0[g * 2 + j] = pk2(s0[g * 4 + 2 * j], s0[g * 4 + 2 * j + 1]);
          pk1[g * 2 + j] = pk2(s1[g * 4 + 2 * j], s1[g * 4 + 2 * j + 1]);
        }
      __builtin_amdgcn_s_setprio(1);
#pragma unroll
      for (int c = 0; c < 4; ++c) {
        const int g0 = (c & 1) * 2, g1 = g0 + 1;
        const unsigned pA0 = (c & 2) ? pk1[g0 * 2 + 0] : pk0[g0 * 2 + 0];
        const unsigned pA1 = (c & 2) ? pk1[g0 * 2 + 1] : pk0[g0 * 2 + 1];
        const unsigned pB0 = (c & 2) ? pk1[g1 * 2 + 0] : pk0[g1 * 2 + 0];
        const unsigned pB1 = (c & 2) ? pk1[g1 * 2 + 1] : pk0[g1 * 2 + 1];
        const unsigned t00 = __shfl_xor((int)pA0, 32);
        const unsigned t01 = __shfl_xor((int)pA1, 32);
        const unsigned t10 = __shfl_xor((int)pB0, 32);
        const unsigned t11 = __shfl_xor((int)pB1, 32);
        union { u4v u; s8v s; } pf;
        pf.u[0] = h8 ? t10 : pA0;
        pf.u[1] = h8 ? t11 : pA1;
        pf.u[2] = h8 ? pB0 : t00;
        pf.u[3] = h8 ? pB1 : t01;
        const s8v vf0 = *(const s8v*)(Vt[cur] + l31 * 72 + c * 16 + h8 * 8);
        const s8v vf1 = *(const s8v*)(Vt[cur] + (32 + l31) * 72 + c * 16 + h8 * 8);
        o0 = MFMA32(vf0, pf.s, o0);
        o1 = MFMA32(vf1, pf.s, o1);
      }
      __builtin_amdgcn_s_setprio(0);
    }
    if (t + 2 <= T) {
      WRITET(cur ^ 1);
      if (t + 4 <= T) LOADT(t + 4);
      __syncthreads();
    }
  }

  // write partials: O^T unnormalized, grouped float4 [kh][h][dgrp][q]
  const size_t obase = (size_t)kh * 12 * 16 * 4096;
#pragma unroll
  for (int g = 0; g < 4; ++g) {
    const float4 v0 = make_float4(o0[g * 4], o0[g * 4 + 1], o0[g * 4 + 2], o0[g * 4 + 3]);
    const float4 v1 = make_float4(o1[g * 4], o1[g * 4 + 1], o1[g * 4 + 2], o1[g * 4 + 3]);
    const int dg0 = 2 * g + h8;
    const int dg1 = 8 + 2 * g + h8;
    Opart[obase + ((size_t)h * 16 + dg0) * 4096 + q_abs] = v0;
    Opart[obase + ((size_t)h * 16 + dg1) * 4096 + q_abs] = v1;
  }
  if (h8 == 0)
    ml[(size_t)kh * 12 * 4096 + (size_t)h * 4096 + q_abs] = make_float2(m_s, l_s);
#undef LOADT
#undef WRITET
}

// ---------------- combine the two key-parity halves -> attn bf16 [q][768] ----------------
__global__ __launch_bounds__(256) void combine_k(const float4* __restrict__ Opart,
    const float2* __restrict__ ml, unsigned short* __restrict__ out) {
  const int t = blockIdx.x * 256 + threadIdx.x;   // 12*4096*64
  const int d = t & 63;
  const int q = (t >> 6) & 4095;
  const int h = t >> 18;
  const float2 e0 = ml[h * 4096 + q];
  const float2 e1 = ml[12 * 4096 + h * 4096 + q];
  const float mx = fmaxf(e0.x, e1.x);
  const float w0 = __expf(e0.x - mx), w1 = __expf(e1.x - mx);
  const float inv = 1.0f / (w0 * e0.y + w1 * e1.y);
  const int dgrp = (d >> 5) * 8 + ((d >> 3) & 3) * 2 + ((d >> 2) & 1);
  const size_t fidx = ((((size_t)h * 16 + dgrp) * 4096 + q) << 2) + (d & 3);
  const float* O0 = (const float*)Opart;
  const float* O1 = O0 + (size_t)12 * 16 * 4096 * 4;
  const float v = (w0 * O0[fidx] + w1 * O1[fidx]) * inv;
  out[(size_t)q * 768 + h * 64 + d] = f2b(v);
}

extern "C" void kernel_launch(void* const* d_in, const int* in_sizes, int n_in,
                              void* d_out, int out_size, void* d_ws, size_t ws_size,
                              hipStream_t stream) {
  const float* x    = (const float*)d_in[0];
  const float* w_q  = (const float*)d_in[1];
  const float* w_k  = (const float*)d_in[2];
  const float* w_v  = (const float*)d_in[3];
  const float* w_o  = (const float*)d_in[4];
  const float* w_g  = (const float*)d_in[5];
  const float* w_u  = (const float*)d_in[6];
  const float* w_d  = (const float*)d_in[7];
  const float* w_n1 = (const float*)d_in[8];
  const float* w_n2 = (const float*)d_in[9];
  (void)in_sizes; (void)n_in; (void)out_size; (void)ws_size;

  char* ws = (char*)d_ws;
  size_t off = 0;
  auto alloc = [&](size_t bytes) { char* p = ws + off; off += (bytes + 255) & ~(size_t)255; return p; };
  unsigned short* wqkvT = (unsigned short*)alloc(2304ull * 768 * 2);
  unsigned short* woT   = (unsigned short*)alloc(768ull * 768 * 2);
  unsigned short* wguT  = (unsigned short*)alloc(4096ull * 768 * 2);
  unsigned short* wdT   = (unsigned short*)alloc(768ull * 2048 * 2);
  float* ct             = (float*)alloc(4096ull * 32 * 4);
  float* st             = (float*)alloc(4096ull * 32 * 4);
  unsigned short* xn    = (unsigned short*)alloc(4096ull * 768 * 2);
  unsigned short* qkv   = (unsigned short*)alloc(4096ull * 2304 * 2);
  unsigned short* attn  = (unsigned short*)alloc(4096ull * 768 * 2);
  float* hbuf           = (float*)alloc(4096ull * 768 * 4);
  unsigned short* ybuf  = (unsigned short*)alloc(4096ull * 768 * 2);
  unsigned short* ffn   = (unsigned short*)alloc(4096ull * 2048 * 2);
  float4* Opart         = (float4*)alloc(2ull * 12 * 16 * 4096 * 16);
  float2* mlb           = (float2*)alloc(2ull * 12 * 4096 * 8);

  PrepArgs pa;
  pa.seg[0] = { w_q, wqkvT,                 768,  768, 24,  576, 0 };
  pa.seg[1] = { w_k, wqkvT + 768 * 768,     768,  768, 24,  576, 0 };
  pa.seg[2] = { w_v, wqkvT + 2 * 768 * 768, 768,  768, 24,  576, 0 };
  pa.seg[3] = { w_o, woT,                   768,  768, 24,  576, 0 };
  pa.seg[4] = { w_g, wguT,                  768, 2048, 64, 1536, 1 };
  pa.seg[5] = { w_u, wguT,                  768, 2048, 64, 1536, 2 };
  pa.seg[6] = { w_d, wdT,                  2048,  768, 24, 1536, 0 };
  pa.seg[7] = { nullptr, nullptr, 0, 0, 0, 512, 3 };
  pa.ct = ct; pa.st = st;
  const int prep_blocks = 576 * 4 + 1536 * 3 + 512;   // 7424

  prep_k<<<prep_blocks, 256, 0, stream>>>(pa);
  rmsnorm_k<<<4096, 256, 0, stream>>>(x, w_n1, xn);
  gemm_bt<2, 128><<<dim3(18, 32), 256, 0, stream>>>(xn, wqkvT, qkv, nullptr, nullptr, 768, 2304, ct, st);
  flash_k<<<dim3(2, 32, 12), 256, 0, stream>>>(qkv, Opart, mlb);
  combine_k<<<12288, 256, 0, stream>>>(Opart, mlb, attn);
  gemm_bt<1, 64><<<dim3(12, 32), 256, 0, stream>>>(attn, woT, nullptr, hbuf, x, 768, 768, nullptr, nullptr);
  rmsnorm_k<<<4096, 256, 0, stream>>>(hbuf, w_n2, ybuf);
  gemm_bt<3, 128><<<dim3(32, 32), 256, 0, stream>>>(ybuf, wguT, ffn, nullptr, nullptr, 768, 2048, nullptr, nullptr);
  gemm_bt<1, 64><<<dim3(12, 32), 256, 0, stream>>>(ffn, wdT, nullptr, (float*)d_out, hbuf, 2048, 768, nullptr, nullptr);
}

// Round 6
// 225.416 us; speedup vs baseline: 1.7225x; 1.0503x over previous
//
#include <hip/hip_runtime.h>
#include <hip/hip_bf16.h>

typedef __attribute__((ext_vector_type(8))) short s8v;
typedef __attribute__((ext_vector_type(4))) float f4v;
typedef __attribute__((ext_vector_type(16))) float f16v;
typedef __attribute__((ext_vector_type(4))) unsigned u4v;

typedef __attribute__((address_space(1))) const void as1_void;
typedef __attribute__((address_space(3))) void as3_void;

__device__ __forceinline__ void gl16(const void* g, void* l) {
  __builtin_amdgcn_global_load_lds((as1_void*)g, (as3_void*)l, 16, 0, 0);
}

__device__ __forceinline__ float b2f(int u) {
  union { float f; unsigned i; } c; c.i = ((unsigned)(u & 0xFFFF)) << 16; return c.f;
}
__device__ __forceinline__ unsigned short f2b(float f) {   // RNE
  union { float f; unsigned i; } c; c.f = f;
  unsigned r = c.i + 0x7FFFu + ((c.i >> 16) & 1u);
  return (unsigned short)(r >> 16);
}
__device__ __forceinline__ unsigned pk2(float lo, float hi) {  // 2xbf16 pack
  unsigned u;
  asm("v_cvt_pk_bf16_f32 %0, %1, %2" : "=v"(u) : "v"(lo), "v"(hi));
  return u;
}

#define MFMA16(a, b, c) __builtin_amdgcn_mfma_f32_16x16x32_bf16((a), (b), (c), 0, 0, 0)
#define MFMA32(a, b, c) __builtin_amdgcn_mfma_f32_32x32x16_bf16((a), (b), (c), 0, 0, 0)

// ---------------- fused prep: all weight converts (+gu interleave) + rope tables ----------------
struct Seg { const float* src; unsigned short* dst; int K; int N; int nbn; int nblocks; int mode; };
struct PrepArgs { Seg seg[8]; float* ct; float* st; };

__global__ __launch_bounds__(256) void prep_k(PrepArgs a) {
  int b = blockIdx.x, si = 0;
  while (si < 7 && b >= a.seg[si].nblocks) { b -= a.seg[si].nblocks; ++si; }
  const Seg s = a.seg[si];
  const int tid = threadIdx.x;
  if (s.mode == 3) {               // rope tables [4096][32]
    const int t = b * 256 + tid;
    const int sq = t >> 5, d = t & 31;
    const float inv = powf(10000.0f, -(float)d * (1.0f / 32.0f));
    const float ang = (float)sq * inv;
    a.ct[t] = cosf(ang);
    a.st[t] = sinf(ang);
    return;
  }
  __shared__ float tile[32][33];
  const int tx = tid & 31, ty = tid >> 5;
  const int bn = b % s.nbn, bk = b / s.nbn;
#pragma unroll
  for (int i = 0; i < 32; i += 8)
    tile[ty + i][tx] = s.src[(size_t)(bk * 32 + ty + i) * s.N + bn * 32 + tx];
  __syncthreads();
#pragma unroll
  for (int i = 0; i < 32; i += 8) {
    int row;
    if (s.mode == 0)      row = bn * 32 + ty + i;
    else                  row = bn * 64 + (s.mode == 2 ? 32 : 0) + ty + i;
    s.dst[(size_t)row * s.K + bk * 32 + tx] = f2b(tile[tx][ty + i]);
  }
}

// ---------------- RMSNorm: fp32 in -> bf16 out, D=768 ----------------
__global__ __launch_bounds__(256) void rmsnorm_k(const float* __restrict__ x,
    const float* __restrict__ w, unsigned short* __restrict__ out) {
  const int row = blockIdx.x, tid = threadIdx.x;
  const float* xr = x + (size_t)row * 768;
  float v0 = xr[tid], v1 = xr[tid + 256], v2 = xr[tid + 512];
  float ss = v0 * v0 + v1 * v1 + v2 * v2;
#pragma unroll
  for (int m = 1; m < 64; m <<= 1) ss += __shfl_xor(ss, m, 64);
  __shared__ float sred[4];
  if ((tid & 63) == 0) sred[tid >> 6] = ss;
  __syncthreads();
  const float tot = sred[0] + sred[1] + sred[2] + sred[3];
  const float rn = rsqrtf(tot * (1.0f / 768.0f) + 1e-6f);
  unsigned short* orow = out + (size_t)row * 768;
  orow[tid]       = f2b(v0 * rn * w[tid]);
  orow[tid + 256] = f2b(v1 * rn * w[tid + 256]);
  orow[tid + 512] = f2b(v2 * rn * w[tid + 512]);
}

// ---------------- GEMM: C[M,N] = A[M,K](bf16) * Bt[N,K](bf16)^T ----------------
// 3-buffer LDS pipeline, counted vmcnt (loads span 2 K-steps), raw s_barrier.
// EPI 1: fp32 store + fp32 residual add
// EPI 2: bf16 store + RoPE on bn<12 (qkv epilogue)
// EPI 3: silu(gate)*up from 32-interleaved B rows -> bf16, ldc=2048
template <int EPI, int BN>
__global__ __launch_bounds__(256) void gemm_bt(const unsigned short* __restrict__ A,
    const unsigned short* __restrict__ Bt, unsigned short* __restrict__ Cb,
    float* __restrict__ Cf, const float* __restrict__ R, int K, int ldc,
    const float* __restrict__ ct, const float* __restrict__ st) {
  constexpr int ABYTES = 128 * 32 * 2;
  constexpr int BBYTES = BN * 32 * 2;
  constexpr int MR = (BN == 128) ? 4 : 2;
  __shared__ unsigned short As[3 * 128 * 32];
  __shared__ unsigned short Bs[3 * BN * 32];
  const int tid = threadIdx.x;
  const int lane = tid & 63, wid = tid >> 6;
  const int wrow = (BN == 128) ? (wid >> 1) * 64 : wid * 32;
  const int wcol = (BN == 128) ? (wid & 1) * 64 : 0;
  const int l15 = lane & 15, l4 = lane >> 4;
  const int bm = blockIdx.y, bn = blockIdx.x;

  f4v acc[MR][4] = {};

  const int o0 = tid * 16, o1 = tid * 16 + 4096;
  const int r0 = o0 >> 6, c0 = o0 & 63;
  const int r1 = o1 >> 6, c1 = o1 & 63;
  const size_t ldab = (size_t)K * 2;
  const char* Abyte = (const char*)A;
  const char* Bbyte = (const char*)Bt;
  const size_t a0 = (size_t)(bm * 128 + r0) * ldab + c0;
  const size_t a1 = (size_t)(bm * 128 + r1) * ldab + c1;
  const size_t b0 = (size_t)(bn * BN + r0) * ldab + c0;
  const size_t b1 = (size_t)(bn * BN + r1) * ldab + c1;   // used only when BN==128
  char* AsB = (char*)As;
  char* BsB = (char*)Bs;
  const int uoff = wid << 10;

#define STAGEK(I, SL) do { const size_t kb = (size_t)(I) * 64;                 \
    char* Aw = AsB + (SL) * ABYTES;                                            \
    char* Bw = BsB + (SL) * BBYTES;                                            \
    gl16(Abyte + a0 + kb, Aw + uoff);                                          \
    gl16(Abyte + a1 + kb, Aw + uoff + 4096);                                   \
    gl16(Bbyte + b0 + kb, Bw + uoff);                                          \
    if constexpr (BN == 128) gl16(Bbyte + b1 + kb, Bw + uoff + 4096); } while (0)

  const int NI = K >> 5;
  STAGEK(0, 0);
  STAGEK(1, 1);
  int sel = 0, nsl = 2;

  for (int i = 0; i < NI; ++i) {
    if (i < NI - 1) {                       // stage(i) landed; stage(i+1) may stay in flight
      if constexpr (BN == 128) asm volatile("s_waitcnt vmcnt(4)" ::: "memory");
      else                     asm volatile("s_waitcnt vmcnt(3)" ::: "memory");
    } else {
      asm volatile("s_waitcnt vmcnt(0)" ::: "memory");
    }
    __builtin_amdgcn_s_barrier();           // all waves: stage(i) visible, buf(i-1) free
    __builtin_amdgcn_sched_barrier(0);
    if (i + 2 < NI) STAGEK(i + 2, nsl);     // overwrite buf(i-1)'s slot, stays in flight
    const char* Ar = AsB + sel * ABYTES;
    const char* Br = BsB + sel * BBYTES;
    s8v af[MR], bf[4];
#pragma unroll
    for (int m = 0; m < MR; ++m)
      af[m] = *(const s8v*)(Ar + (wrow + m * 16 + l15) * 64 + l4 * 16);
#pragma unroll
    for (int n = 0; n < 4; ++n)
      bf[n] = *(const s8v*)(Br + (wcol + n * 16 + l15) * 64 + l4 * 16);
    __builtin_amdgcn_s_setprio(1);
#pragma unroll
    for (int m = 0; m < MR; ++m)
#pragma unroll
      for (int n = 0; n < 4; ++n) acc[m][n] = MFMA16(af[m], bf[n], acc[m][n]);
    __builtin_amdgcn_s_setprio(0);
    sel = (sel == 2) ? 0 : sel + 1;
    nsl = (nsl == 2) ? 0 : nsl + 1;
  }
#undef STAGEK

  const int row0 = bm * 128 + wrow;
  const int col0 = bn * BN + wcol;

  if (EPI == 2 && bn < 12) {       // RoPE in-register: pair (m,n) with (m,n+2)
#pragma unroll
    for (int m = 0; m < MR; ++m)
#pragma unroll
      for (int r = 0; r < 4; ++r) {
        const int row = row0 + m * 16 + l4 * 4 + r;
#pragma unroll
        for (int n = 0; n < 2; ++n) {
          const int d = n * 16 + l15;
          const float c  = ct[row * 32 + d];
          const float sn = st[row * 32 + d];
          const float aa = acc[m][n][r], bb = acc[m][n + 2][r];
          acc[m][n][r]     = aa * c - bb * sn;
          acc[m][n + 2][r] = bb * c + aa * sn;
        }
      }
  }

  if (EPI == 3) {                  // silu(g)*u, g at n<2, u at n+2
    const int wcx = wcol >> 6;
    const int colb = (bn * 2 + wcx) * 32;
#pragma unroll
    for (int m = 0; m < MR; ++m)
#pragma unroll
      for (int n = 0; n < 2; ++n)
#pragma unroll
        for (int r = 0; r < 4; ++r) {
          const int row = row0 + m * 16 + l4 * 4 + r;
          const float g = acc[m][n][r], u = acc[m][n + 2][r];
          const float val = g * u / (1.0f + __expf(-g));
          Cb[(size_t)row * 2048 + colb + n * 16 + l15] = f2b(val);
        }
    return;
  }

#pragma unroll
  for (int m = 0; m < MR; ++m)
#pragma unroll
    for (int n = 0; n < 4; ++n)
#pragma unroll
      for (int r = 0; r < 4; ++r) {
        const int row = row0 + m * 16 + l4 * 4 + r;
        const int col = col0 + n * 16 + l15;
        const float v = acc[m][n][r];
        if (EPI == 1) {
          Cf[(size_t)row * ldc + col] = v + R[(size_t)row * ldc + col];
        } else {
          Cb[(size_t)row * ldc + col] = f2b(v);
        }
      }
}

// ---------------- causal flash attention: 32x32 swapped-QK, balanced pairs (round-4) ----------------
// grid (kh=2, p=32, h=12). Block: waves 0,2 = qbA rows 0-31/32-63; waves 1,3 = qbB.
// Processes KV tiles t == kh (mod 2); partial (m,l,O^T) written for combine_k.
__global__ __launch_bounds__(256, 3) void flash_k(const unsigned short* __restrict__ qkv,
    float4* __restrict__ Opart, float2* __restrict__ ml) {
  const int kh = blockIdx.x, p = blockIdx.y, h = blockIdx.z;
  const int qbA = 63 - p;
  const int tid = threadIdx.x;
  const int wv = tid >> 6, lane = tid & 63;
  const int l31 = lane & 31, h8 = lane >> 5;
  const int myqb = (wv & 1) ? p : qbA;
  const int qrel = (wv >> 1) * 32 + l31;
  const int q_abs = myqb * 64 + qrel;

  __shared__ unsigned short Ks[2][64 * 72];   // [key][d], 72-padded
  __shared__ unsigned short Vt[2][64 * 72];   // [d][key], 72-padded (transposed)

  const unsigned short* qp = qkv + h * 64;
  const unsigned short* kp = qkv + 768 + h * 64;
  const unsigned short* vp = qkv + 1536 + h * 64;

  s8v qf[4];                                  // Q B-frags, whole kernel
#pragma unroll
  for (int c = 0; c < 4; ++c)
    qf[c] = *(const s8v*)(qp + (size_t)q_abs * 2304 + c * 16 + h8 * 8);

  f16v o0 = {}, o1 = {};                      // O^T acc, d-tiles 0/1
  float m_s = -1e30f, l_s = 0.f;

  const int krow = tid >> 3, kc = (tid & 7) * 8;
  const int vj = tid & 31, vd0 = (tid >> 5) * 8;

  s8v ka, kb, va, vb;
#define LOADT(T) do { const size_t k0n = (size_t)(T) * 64;                    \
    ka = *(const s8v*)(kp + (k0n + krow) * 2304 + kc);                        \
    kb = *(const s8v*)(kp + (k0n + krow + 32) * 2304 + kc);                   \
    va = *(const s8v*)(vp + (k0n + 2 * vj) * 2304 + vd0);                     \
    vb = *(const s8v*)(vp + (k0n + 2 * vj + 1) * 2304 + vd0); } while (0)
#define WRITET(BUF) do {                                                      \
    *(s8v*)(Ks[BUF] + krow * 72 + kc) = ka;                                   \
    *(s8v*)(Ks[BUF] + (krow + 32) * 72 + kc) = kb;                            \
    unsigned* vtw = (unsigned*)(Vt[BUF] + (size_t)vd0 * 72 + 2 * vj);         \
    _Pragma("unroll")                                                         \
    for (int i = 0; i < 8; ++i)                                               \
      vtw[i * 36] = ((unsigned)(unsigned short)va[i]) |                       \
                    (((unsigned)(unsigned short)vb[i]) << 16); } while (0)

  LOADT(kh);
  WRITET(0);
  if (kh + 2 <= qbA) LOADT(kh + 2);
  __syncthreads();

  for (int t = kh; t <= qbA; t += 2) {
    const int cur = (t >> 1) & 1;
    if (t <= myqb) {
      // S^T[key][q] = K * Q^T (swapped): lane q=l31, 32 keys split by h8
      f16v s0 = {}, s1 = {};
      __builtin_amdgcn_s_setprio(1);
#pragma unroll
      for (int c = 0; c < 4; ++c) {
        const s8v kf0 = *(const s8v*)(Ks[cur] + l31 * 72 + c * 16 + h8 * 8);
        const s8v kf1 = *(const s8v*)(Ks[cur] + (32 + l31) * 72 + c * 16 + h8 * 8);
        s0 = MFMA32(kf0, qf[c], s0);
        s1 = MFMA32(kf1, qf[c], s1);
      }
      __builtin_amdgcn_s_setprio(0);
#pragma unroll
      for (int r = 0; r < 16; ++r) { s0[r] *= 0.125f; s1[r] *= 0.125f; }
      if (t == myqb) {                       // diagonal tile: causal mask
#pragma unroll
        for (int r = 0; r < 16; ++r) {
          const int koff = (r & 3) + 8 * (r >> 2) + 4 * h8;
          if (koff > qrel) s0[r] = -1e30f;
          if (koff + 32 > qrel) s1[r] = -1e30f;
        }
      }
      // row max: in-lane tree + one cross-half shuffle
      float red[8];
#pragma unroll
      for (int i = 0; i < 8; ++i)
        red[i] = fmaxf(fmaxf(s0[i], s0[i + 8]), fmaxf(s1[i], s1[i + 8]));
#pragma unroll
      for (int i = 0; i < 4; ++i) red[i] = fmaxf(red[i], red[i + 4]);
      float mloc = fmaxf(fmaxf(red[0], red[1]), fmaxf(red[2], red[3]));
      mloc = fmaxf(mloc, __shfl_xor(mloc, 32));
      if (__any(mloc > m_s + 8.f)) {         // defer-max
        const float mn = fmaxf(m_s, mloc);
        const float corr = __expf(m_s - mn);
        m_s = mn; l_s *= corr;
#pragma unroll
        for (int r = 0; r < 16; ++r) { o0[r] *= corr; o1[r] *= corr; }
      }
#pragma unroll
      for (int r = 0; r < 16; ++r) {
        s0[r] = __expf(s0[r] - m_s);
        s1[r] = __expf(s1[r] - m_s);
      }
      float sm[8];
#pragma unroll
      for (int i = 0; i < 8; ++i) sm[i] = (s0[i] + s0[i + 8]) + (s1[i] + s1[i + 8]);
#pragma unroll
      for (int i = 0; i < 4; ++i) sm[i] += sm[i + 4];
      float ps = (sm[0] + sm[1]) + (sm[2] + sm[3]);
      ps += __shfl_xor(ps, 32);
      l_s += ps;

      // pack P to bf16 pairs; cross-half redistribute into PV B-frags
      unsigned pk0[8], pk1[8];
#pragma unroll
      for (int g = 0; g < 4; ++g)
#pragma unroll
        for (int j = 0; j < 2; ++j) {
          pk0[g * 2 + j] = pk2(s0[g * 4 + 2 * j], s0[g * 4 + 2 * j + 1]);
          pk1[g * 2 + j] = pk2(s1[g * 4 + 2 * j], s1[g * 4 + 2 * j + 1]);
        }
      __builtin_amdgcn_s_setprio(1);
#pragma unroll
      for (int c = 0; c < 4; ++c) {
        const int g0 = (c & 1) * 2, g1 = g0 + 1;
        const unsigned pA0 = (c & 2) ? pk1[g0 * 2 + 0] : pk0[g0 * 2 + 0];
        const unsigned pA1 = (c & 2) ? pk1[g0 * 2 + 1] : pk0[g0 * 2 + 1];
        const unsigned pB0 = (c & 2) ? pk1[g1 * 2 + 0] : pk0[g1 * 2 + 0];
        const unsigned pB1 = (c & 2) ? pk1[g1 * 2 + 1] : pk0[g1 * 2 + 1];
        const unsigned t00 = __shfl_xor((int)pA0, 32);
        const unsigned t01 = __shfl_xor((int)pA1, 32);
        const unsigned t10 = __shfl_xor((int)pB0, 32);
        const unsigned t11 = __shfl_xor((int)pB1, 32);
        union { u4v u; s8v s; } pf;
        pf.u[0] = h8 ? t10 : pA0;
        pf.u[1] = h8 ? t11 : pA1;
        pf.u[2] = h8 ? pB0 : t00;
        pf.u[3] = h8 ? pB1 : t01;
        const s8v vf0 = *(const s8v*)(Vt[cur] + l31 * 72 + c * 16 + h8 * 8);
        const s8v vf1 = *(const s8v*)(Vt[cur] + (32 + l31) * 72 + c * 16 + h8 * 8);
        o0 = MFMA32(vf0, pf.s, o0);
        o1 = MFMA32(vf1, pf.s, o1);
      }
      __builtin_amdgcn_s_setprio(0);
    }
    if (t + 2 <= qbA) {
      WRITET(cur ^ 1);
      if (t + 4 <= qbA) LOADT(t + 4);
      __syncthreads();
    }
  }

  // write partials: O^T unnormalized, grouped float4 [kh][h][dgrp][q]
  const size_t obase = (size_t)kh * 12 * 16 * 4096;
#pragma unroll
  for (int g = 0; g < 4; ++g) {
    const float4 v0 = make_float4(o0[g * 4], o0[g * 4 + 1], o0[g * 4 + 2], o0[g * 4 + 3]);
    const float4 v1 = make_float4(o1[g * 4], o1[g * 4 + 1], o1[g * 4 + 2], o1[g * 4 + 3]);
    const int dg0 = 2 * g + h8;
    const int dg1 = 8 + 2 * g + h8;
    Opart[obase + ((size_t)h * 16 + dg0) * 4096 + q_abs] = v0;
    Opart[obase + ((size_t)h * 16 + dg1) * 4096 + q_abs] = v1;
  }
  if (h8 == 0)
    ml[(size_t)kh * 12 * 4096 + (size_t)h * 4096 + q_abs] = make_float2(m_s, l_s);
#undef LOADT
#undef WRITET
}

// ---------------- combine halves -> attn bf16 [q][768]; coalesced reads, 8B writes ----------------
__global__ __launch_bounds__(256) void combine_k(const float4* __restrict__ Opart,
    const float2* __restrict__ ml, unsigned short* __restrict__ out) {
  const int u = blockIdx.x * 256 + threadIdx.x;   // 12*16*4096 threads
  const int q = u & 4095;
  const int rest = u >> 12;
  const int dgrp = rest & 15;
  const int h = rest >> 4;
  const float2 e0 = ml[h * 4096 + q];
  const float2 e1 = ml[12 * 4096 + h * 4096 + q];
  const float mx = fmaxf(e0.x, e1.x);
  const float w0 = __expf(e0.x - mx), w1 = __expf(e1.x - mx);
  const float inv = 1.0f / (w0 * e0.y + w1 * e1.y);
  const size_t idx = ((size_t)h * 16 + dgrp) * 4096 + q;
  const float4 a = Opart[idx];
  const float4 b = Opart[(size_t)12 * 16 * 4096 + idx];
  const int dbase = (dgrp < 8) ? 4 * dgrp : 32 + 4 * (dgrp - 8);
  ushort4 r;
  r.x = f2b((w0 * a.x + w1 * b.x) * inv);
  r.y = f2b((w0 * a.y + w1 * b.y) * inv);
  r.z = f2b((w0 * a.z + w1 * b.z) * inv);
  r.w = f2b((w0 * a.w + w1 * b.w) * inv);
  *(ushort4*)(out + (size_t)q * 768 + h * 64 + dbase) = r;
}

extern "C" void kernel_launch(void* const* d_in, const int* in_sizes, int n_in,
                              void* d_out, int out_size, void* d_ws, size_t ws_size,
                              hipStream_t stream) {
  const float* x    = (const float*)d_in[0];
  const float* w_q  = (const float*)d_in[1];
  const float* w_k  = (const float*)d_in[2];
  const float* w_v  = (const float*)d_in[3];
  const float* w_o  = (const float*)d_in[4];
  const float* w_g  = (const float*)d_in[5];
  const float* w_u  = (const float*)d_in[6];
  const float* w_d  = (const float*)d_in[7];
  const float* w_n1 = (const float*)d_in[8];
  const float* w_n2 = (const float*)d_in[9];
  (void)in_sizes; (void)n_in; (void)out_size; (void)ws_size;

  char* ws = (char*)d_ws;
  size_t off = 0;
  auto alloc = [&](size_t bytes) { char* p = ws + off; off += (bytes + 255) & ~(size_t)255; return p; };
  unsigned short* wqkvT = (unsigned short*)alloc(2304ull * 768 * 2);
  unsigned short* woT   = (unsigned short*)alloc(768ull * 768 * 2);
  unsigned short* wguT  = (unsigned short*)alloc(4096ull * 768 * 2);
  unsigned short* wdT   = (unsigned short*)alloc(768ull * 2048 * 2);
  float* ct             = (float*)alloc(4096ull * 32 * 4);
  float* st             = (float*)alloc(4096ull * 32 * 4);
  unsigned short* xn    = (unsigned short*)alloc(4096ull * 768 * 2);
  unsigned short* qkv   = (unsigned short*)alloc(4096ull * 2304 * 2);
  unsigned short* attn  = (unsigned short*)alloc(4096ull * 768 * 2);
  float* hbuf           = (float*)alloc(4096ull * 768 * 4);
  unsigned short* ybuf  = (unsigned short*)alloc(4096ull * 768 * 2);
  unsigned short* ffn   = (unsigned short*)alloc(4096ull * 2048 * 2);
  float4* Opart         = (float4*)alloc(2ull * 12 * 16 * 4096 * 16);
  float2* mlb           = (float2*)alloc(2ull * 12 * 4096 * 8);

  PrepArgs pa;
  pa.seg[0] = { w_q, wqkvT,                 768,  768, 24,  576, 0 };
  pa.seg[1] = { w_k, wqkvT + 768 * 768,     768,  768, 24,  576, 0 };
  pa.seg[2] = { w_v, wqkvT + 2 * 768 * 768, 768,  768, 24,  576, 0 };
  pa.seg[3] = { w_o, woT,                   768,  768, 24,  576, 0 };
  pa.seg[4] = { w_g, wguT,                  768, 2048, 64, 1536, 1 };
  pa.seg[5] = { w_u, wguT,                  768, 2048, 64, 1536, 2 };
  pa.seg[6] = { w_d, wdT,                  2048,  768, 24, 1536, 0 };
  pa.seg[7] = { nullptr, nullptr, 0, 0, 0, 512, 3 };
  pa.ct = ct; pa.st = st;
  const int prep_blocks = 576 * 4 + 1536 * 3 + 512;   // 7424

  prep_k<<<prep_blocks, 256, 0, stream>>>(pa);
  rmsnorm_k<<<4096, 256, 0, stream>>>(x, w_n1, xn);
  gemm_bt<2, 128><<<dim3(18, 32), 256, 0, stream>>>(xn, wqkvT, qkv, nullptr, nullptr, 768, 2304, ct, st);
  flash_k<<<dim3(2, 32, 12), 256, 0, stream>>>(qkv, Opart, mlb);
  combine_k<<<3072, 256, 0, stream>>>(Opart, mlb, attn);
  gemm_bt<1, 64><<<dim3(12, 32), 256, 0, stream>>>(attn, woT, nullptr, hbuf, x, 768, 768, nullptr, nullptr);
  rmsnorm_k<<<4096, 256, 0, stream>>>(hbuf, w_n2, ybuf);
  gemm_bt<3, 128><<<dim3(32, 32), 256, 0, stream>>>(ybuf, wguT, ffn, nullptr, nullptr, 768, 2048, nullptr, nullptr);
  gemm_bt<1, 64><<<dim3(12, 32), 256, 0, stream>>>(ffn, wdT, nullptr, (float*)d_out, hbuf, 2048, 768, nullptr, nullptr);
}